// Round 1
// baseline (15090.401 us; speedup 1.0000x reference)
//
#include <hip/hip_runtime.h>
#include <math.h>

// Problem constants (match setup_inputs)
#define B_ROWS 2048
#define N_ANCH 50000
#define DIM    256
#define TOPK   50

// K1 tiling
#define BT 64          // feature rows per block
#define AT 256         // anchors per tile
#define KC 32          // K chunk staged in LDS
#define NCH 16         // anchor chunks (50000/16 = 3125 exactly)
#define CHUNK 3125
#define NTILES 13      // ceil(3125/256)

#define SU_ANC_STRIDE 260   // anchor tile LDS row stride (k-major), b128-aligned, 2-way read alias
#define SU_STG_STRIDE 262   // sim staging stride (row-major), conflict-friendly for owner scan
#define SU_SIZE (32*SU_STG_STRIDE)   // union buffer: anchors (32*260) / sim staging (32*262)
#define SF_STRIDE 68        // feat tile LDS row stride

// K1: fused tiled fp32 GEMM + exact per-(row,chunk) top-50.
// block tile: 64 rows x 256 anchors, 256 threads, 8x8 register micro-tile.
__global__ __launch_bounds__(256, 2)
void knn_chunk_topk(const float* __restrict__ feat,
                    const float* __restrict__ anc,
                    float* __restrict__ cv,
                    int*   __restrict__ ci)
{
    __shared__ float sU[SU_SIZE];          // anchors (k-major) OR sim staging (row-major)
    __shared__ float sF[KC*SF_STRIDE];     // features, k-major
    __shared__ float s_topv[BT][TOPK];     // sorted desc
    __shared__ int   s_topi[BT][TOPK];
    __shared__ float s_rowmin[BT];         // current 50th value (or -inf while filling)
    __shared__ int   s_flag[BT];
    __shared__ int   s_cnt[BT];

    const int tid = threadIdx.x;
    const int rg  = tid >> 5;      // 0..7  -> rows rg*8..rg*8+7
    const int ag  = tid & 31;      // 0..31 -> anchors ag*8..ag*8+7
    const int rbase = blockIdx.x * BT;
    const int cbase = blockIdx.y * CHUNK;

    if (tid < BT) { s_cnt[tid] = 0; s_rowmin[tid] = -INFINITY; s_flag[tid] = 0; }

    const float4* A4 = (const float4*)anc;
    const float4* F4 = (const float4*)feat;

    for (int tile = 0; tile < NTILES; ++tile) {
        const int abase = cbase + tile * AT;
        const int valid = min(AT, cbase + CHUNK - abase);   // tail tile: 53

        float acc[8][8];
        #pragma unroll
        for (int i = 0; i < 8; ++i)
            #pragma unroll
            for (int j = 0; j < 8; ++j) acc[i][j] = 0.f;

        for (int kc = 0; kc < DIM/KC; ++kc) {
            __syncthreads();   // sU/sF free (prev GEMM reads or prev owner scan done)
            // stage 256 anchors x 32 k (coalesced float4 loads, transposed store)
            #pragma unroll
            for (int it = 0; it < 8; ++it) {
                int flat = tid + 256*it;
                int a = flat >> 3, k4 = flat & 7;
                int ga = abase + a; if (ga >= N_ANCH) ga = N_ANCH - 1;  // clamp; never scanned
                float4 v = A4[(size_t)ga*(DIM/4) + kc*8 + k4];
                sU[(k4*4+0)*SU_ANC_STRIDE + a] = v.x;
                sU[(k4*4+1)*SU_ANC_STRIDE + a] = v.y;
                sU[(k4*4+2)*SU_ANC_STRIDE + a] = v.z;
                sU[(k4*4+3)*SU_ANC_STRIDE + a] = v.w;
            }
            // stage 64 rows x 32 k
            #pragma unroll
            for (int it = 0; it < 2; ++it) {
                int flat = tid + 256*it;
                int r = flat >> 3, k4 = flat & 7;
                float4 v = F4[(size_t)(rbase + r)*(DIM/4) + kc*8 + k4];
                sF[(k4*4+0)*SF_STRIDE + r] = v.x;
                sF[(k4*4+1)*SF_STRIDE + r] = v.y;
                sF[(k4*4+2)*SF_STRIDE + r] = v.z;
                sF[(k4*4+3)*SF_STRIDE + r] = v.w;
            }
            __syncthreads();
            #pragma unroll 4
            for (int k = 0; k < KC; ++k) {
                float4 f0 = *(const float4*)&sF[k*SF_STRIDE + rg*8];
                float4 f1 = *(const float4*)&sF[k*SF_STRIDE + rg*8 + 4];
                float4 a0 = *(const float4*)&sU[k*SU_ANC_STRIDE + ag*8];
                float4 a1 = *(const float4*)&sU[k*SU_ANC_STRIDE + ag*8 + 4];
                float fr[8] = {f0.x,f0.y,f0.z,f0.w,f1.x,f1.y,f1.z,f1.w};
                float ar[8] = {a0.x,a0.y,a0.z,a0.w,a1.x,a1.y,a1.z,a1.w};
                #pragma unroll
                for (int i = 0; i < 8; ++i)
                    #pragma unroll
                    for (int j = 0; j < 8; ++j)
                        acc[i][j] = fmaf(fr[i], ar[j], acc[i][j]);
            }
        }

        // candidate flags from registers (snapshot rowmin; false positives ok, no false negatives)
        float rmin[8];
        #pragma unroll
        for (int i = 0; i < 8; ++i) rmin[i] = s_rowmin[rg*8 + i];
        #pragma unroll
        for (int i = 0; i < 8; ++i) {
            bool any = false;
            #pragma unroll
            for (int j = 0; j < 8; ++j) any = any || (acc[i][j] > rmin[i]);
            if (any) s_flag[rg*8 + i] = 1;
        }

        // two half-tile phases: stage 32 rows x 256 sims into sU, owner lanes insert
        for (int p = 0; p < 2; ++p) {
            __syncthreads();   // sU free for staging
            if ((rg >> 2) == p) {
                const int rl0 = (rg & 3) * 8;
                #pragma unroll
                for (int i = 0; i < 8; ++i) {
                    #pragma unroll
                    for (int jj = 0; jj < 4; ++jj) {
                        *(float2*)&sU[(rl0+i)*SU_STG_STRIDE + ag*8 + 2*jj] =
                            make_float2(acc[i][2*jj], acc[i][2*jj+1]);
                    }
                }
            }
            __syncthreads();
            if (tid < 32) {
                const int R = p*32 + tid;
                if (s_flag[R]) {
                    int cnt = s_cnt[R];
                    float minv = (cnt < TOPK) ? -INFINITY : s_topv[R][TOPK-1];
                    for (int a = 0; a < valid; ++a) {
                        float v = sU[tid*SU_STG_STRIDE + a];
                        if (cnt < TOPK || v > minv) {
                            int j = (cnt < TOPK) ? cnt : (TOPK-1);
                            while (j > 0 && s_topv[R][j-1] < v) {   // stable: ties keep earlier index first
                                s_topv[R][j] = s_topv[R][j-1];
                                s_topi[R][j] = s_topi[R][j-1];
                                --j;
                            }
                            s_topv[R][j] = v;
                            s_topi[R][j] = abase + a;
                            if (cnt < TOPK) ++cnt;
                            if (cnt >= TOPK) minv = s_topv[R][TOPK-1];
                        }
                    }
                    s_cnt[R] = cnt;
                    s_rowmin[R] = (cnt < TOPK) ? -INFINITY : minv;
                    s_flag[R] = 0;
                }
            }
        }
    }
    __syncthreads();
    // write per-(row,chunk) top-50 candidates
    for (int e = tid; e < BT*TOPK; e += 256) {
        int row = e / TOPK, j = e % TOPK;
        size_t g = ((size_t)(rbase + row) * NCH + blockIdx.y) * TOPK + j;
        cv[g] = s_topv[row][j];
        ci[g] = s_topi[row][j];
    }
}

// K2: exact merge of 16 sorted runs of 50 -> top-50, then loss / mean_sim.
__global__ __launch_bounds__(256)
void knn_merge(const float* __restrict__ cv, const int* __restrict__ ci,
               const int* __restrict__ labels, const int* __restrict__ anchor_label,
               float* __restrict__ out)
{
    const int M = NCH * TOPK;   // 800
    __shared__ float s_val[NCH*TOPK];
    __shared__ int   s_idx[NCH*TOPK];
    __shared__ float s_sv[NCH*TOPK];
    __shared__ int   s_si[NCH*TOPK];
    __shared__ float s_T;
    __shared__ int   s_ns;
    __shared__ float s_sum;
    __shared__ int   s_cnt;

    const int row = blockIdx.x;
    const int tid = threadIdx.x;

    if (tid == 0) { s_ns = 0; s_sum = 0.f; s_cnt = 0; }
    for (int e = tid; e < M; e += 256) {
        s_val[e] = cv[(size_t)row*M + e];
        s_idx[e] = ci[(size_t)row*M + e];
    }
    __syncthreads();
    if (tid == 0) {
        // lower bound on the 50th-largest: best single run already has 50 values >= its own [49]
        float t = -INFINITY;
        for (int c = 0; c < NCH; ++c) t = fmaxf(t, s_val[c*TOPK + TOPK-1]);
        s_T = t;
    }
    __syncthreads();
    const float T = s_T;
    for (int e = tid; e < M; e += 256) {
        float v = s_val[e];
        if (v >= T) {
            int p = atomicAdd(&s_ns, 1);
            s_sv[p] = v; s_si[p] = s_idx[e];
        }
    }
    __syncthreads();
    const int ns = s_ns;             // >= 50 guaranteed
    const int mylab = labels[row];
    for (int s = tid; s < ns; s += 256) {
        float v = s_sv[s]; int id = s_si[s];
        int r = 0;
        for (int q = 0; q < ns; ++q) {
            float vq = s_sv[q];
            r += (vq > v) || (vq == v && s_si[q] < id);   // jax tie-break: smaller index wins
        }
        if (r < TOPK) {
            atomicAdd(&s_sum, v);
            if (anchor_label[id] == mylab) atomicAdd(&s_cnt, 1);
        }
    }
    __syncthreads();
    if (tid == 0) {
        float mlp = (float)s_cnt / (float)TOPK;   // never NaN; ref's NaN-scrub is a no-op here
        out[row]          = -mlp;                 // loss
        out[B_ROWS + row] = s_sum / (float)TOPK;  // mean_sim
    }
}

extern "C" void kernel_launch(void* const* d_in, const int* in_sizes, int n_in,
                              void* d_out, int out_size, void* d_ws, size_t ws_size,
                              hipStream_t stream)
{
    const float* feat         = (const float*)d_in[0];
    const float* anc          = (const float*)d_in[1];
    const int*   labels       = (const int*)d_in[2];
    // d_in[3] = t_labels (unused by reference)
    const int*   anchor_label = (const int*)d_in[4];
    float* out = (float*)d_out;

    float* cv = (float*)d_ws;                                                   // 2048*800 fp32 = 6.55 MB
    int*   ci = (int*)((char*)d_ws + (size_t)B_ROWS*NCH*TOPK*sizeof(float));    // 2048*800 i32  = 6.55 MB

    hipLaunchKernelGGL(knn_chunk_topk, dim3(B_ROWS/BT, NCH), dim3(256), 0, stream,
                       feat, anc, cv, ci);
    hipLaunchKernelGGL(knn_merge, dim3(B_ROWS), dim3(256), 0, stream,
                       cv, ci, labels, anchor_label, out);
}

// Round 3
// 4665.149 us; speedup vs baseline: 3.2347x; 3.2347x over previous
//
#include <hip/hip_runtime.h>
#include <math.h>

// Problem constants (match setup_inputs)
#define B_ROWS 2048
#define N_ANCH 50000
#define DIM    256
#define TOPK   50

// K1 tiling
#define BT 64          // feature rows per block
#define AT 256         // anchors per tile
#define KC 32          // K chunk staged in LDS
#define NCH 16         // anchor chunks (50000/16 = 3125 exactly)
#define CHUNK 3125
#define NTILES 13      // ceil(3125/256)

#define SU_ANC_STRIDE 260   // anchor tile LDS row stride (floats); 1040 B keeps 16B align
#define SF_STRIDE 68        // feat tile LDS row stride

__device__ __forceinline__ bool lex_better(float v1, int i1, float v2, int i2) {
    // "better" = ranked higher by jax top_k: larger value, ties -> smaller index
    return (v1 > v2) || (v1 == v2 && i1 < i2);
}

// K1: fused tiled fp32 GEMM + exact per-(row,chunk) top-50 (unsorted set).
// block tile: 64 rows x 256 anchors, 256 threads, 8x8 register micro-tile.
// Top-k via capped candidate-push + 64 parallel replace-min owners.
__global__ __launch_bounds__(256, 2)
void knn_chunk_topk(const float* __restrict__ feat,
                    const float* __restrict__ anc,
                    float* __restrict__ cv,
                    int*   __restrict__ ci)
{
    __shared__ __align__(16) float sU[32*SU_ANC_STRIDE]; // anchors (GEMM) / cand buffer (select)
    __shared__ float sF[KC*SF_STRIDE];                   // features, k-major
    __shared__ float s_topv[BT][TOPK];                   // UNSORTED top-50 values
    __shared__ int   s_topi[BT][TOPK];
    __shared__ float s_rowmin[BT];                       // current 50th-best (-inf while filling)
    __shared__ unsigned char s_npush[BT][32];            // pushes this round per (row,lane)
    __shared__ int   s_more[2];

    uint2* cand = (uint2*)sU;                            // [BT][32][2] (32 KB <= 33.3 KB of sU)

    const int tid = threadIdx.x;
    const int rg  = tid >> 5;      // 0..7  -> rows rg*8..rg*8+7
    const int ag  = tid & 31;      // 0..31 -> anchors {4ag..4ag+3} U {128+4ag..128+4ag+3}
    const int rbase = blockIdx.x * BT;
    const int cbase = blockIdx.y * CHUNK;

    if (tid < BT) s_rowmin[tid] = -INFINITY;

    // owner state lives in registers; thread 4*r owns row r
    int   o_cnt = 0;
    float o_minv = 0.f;
    int   o_minidx = 0, o_minpos = 0;
    const int  o_row   = tid >> 2;
    const bool is_owner = (tid & 3) == 0;

    const float4* A4 = (const float4*)anc;
    const float4* F4 = (const float4*)feat;

    for (int tile = 0; tile < NTILES; ++tile) {
        const int abase = cbase + tile * AT;
        const int valid = min(AT, cbase + CHUNK - abase);   // tail tile: 53

        float acc[8][8];
        #pragma unroll
        for (int i = 0; i < 8; ++i)
            #pragma unroll
            for (int j = 0; j < 8; ++j) acc[i][j] = 0.f;

        for (int kc = 0; kc < DIM/KC; ++kc) {
            __syncthreads();   // sU/sF free (prev GEMM reads / prev owner phase done)
            // stage 256 anchors x 32 k (coalesced float4 loads, transposed store)
            #pragma unroll
            for (int it = 0; it < 8; ++it) {
                int flat = tid + 256*it;
                int a = flat >> 3, k4 = flat & 7;
                int ga = abase + a; if (ga >= N_ANCH) ga = N_ANCH - 1;  // clamp; masked in push
                float4 v = A4[(size_t)ga*(DIM/4) + kc*8 + k4];
                sU[(k4*4+0)*SU_ANC_STRIDE + a] = v.x;
                sU[(k4*4+1)*SU_ANC_STRIDE + a] = v.y;
                sU[(k4*4+2)*SU_ANC_STRIDE + a] = v.z;
                sU[(k4*4+3)*SU_ANC_STRIDE + a] = v.w;
            }
            // stage 64 rows x 32 k
            #pragma unroll
            for (int it = 0; it < 2; ++it) {
                int flat = tid + 256*it;
                int r = flat >> 3, k4 = flat & 7;
                float4 v = F4[(size_t)(rbase + r)*(DIM/4) + kc*8 + k4];
                sF[(k4*4+0)*SF_STRIDE + r] = v.x;
                sF[(k4*4+1)*SF_STRIDE + r] = v.y;
                sF[(k4*4+2)*SF_STRIDE + r] = v.z;
                sF[(k4*4+3)*SF_STRIDE + r] = v.w;
            }
            __syncthreads();
            #pragma unroll 4
            for (int k = 0; k < KC; ++k) {
                float4 f0 = *(const float4*)&sF[k*SF_STRIDE + rg*8];
                float4 f1 = *(const float4*)&sF[k*SF_STRIDE + rg*8 + 4];
                // split anchor fragment: lane addresses contiguous 16B -> conflict-free
                float4 a0 = *(const float4*)&sU[k*SU_ANC_STRIDE + 4*ag];
                float4 a1 = *(const float4*)&sU[k*SU_ANC_STRIDE + 128 + 4*ag];
                float fr[8] = {f0.x,f0.y,f0.z,f0.w,f1.x,f1.y,f1.z,f1.w};
                float ar[8] = {a0.x,a0.y,a0.z,a0.w,a1.x,a1.y,a1.z,a1.w};
                #pragma unroll
                for (int i = 0; i < 8; ++i)
                    #pragma unroll
                    for (int j = 0; j < 8; ++j)
                        acc[i][j] = fmaf(fr[i], ar[j], acc[i][j]);
            }
        }

        // ---- candidate selection rounds (buffer aliases sU) ----
        if (tid == 0) { s_more[0] = 0; s_more[1] = 0; }
        __syncthreads();   // GEMM reads of sU done; flags cleared

        unsigned rmask[8];
        #pragma unroll
        for (int i = 0; i < 8; ++i) rmask[i] = 0xFFu;

        int p = 0;
        for (int round = 0; round < 6; ++round) {
            // push phase: every lane, <=2 candidates per row, deterministic slots
            #pragma unroll
            for (int i = 0; i < 8; ++i) {
                const int r = rg*8 + i;
                const float rmv = s_rowmin[r];
                int cnt = 0;
                unsigned m = rmask[i];
                if (m) {
                    #pragma unroll
                    for (int j = 0; j < 8; ++j) {
                        if (m & (1u<<j)) {
                            const int aoff = (j < 4) ? (4*ag + j) : (124 + 4*ag + j);
                            const float v = acc[i][j];
                            if (aoff < valid && v >= rmv) {
                                if (cnt < 2) {
                                    cand[(r*32 + ag)*2 + cnt] =
                                        make_uint2(__float_as_uint(v), (unsigned)(abase + aoff));
                                    m &= ~(1u<<j);
                                    ++cnt;
                                } else {
                                    s_more[p] = 1;      // deferred; retry next round
                                }
                            } else {
                                m &= ~(1u<<j);          // rejected (rowmin only rises) or OOB
                            }
                        }
                    }
                    rmask[i] = m;
                }
                s_npush[r][ag] = (unsigned char)cnt;    // always write (0 clears stale)
            }
            if (tid == 0) s_more[p^1] = 0;
            __syncthreads();
            const int more = s_more[p];                  // read between barriers: uniform
            // owner phase: 64 owners (16 per wave), replace-min, fixed-50 rescan
            if (is_owner) {
                const int r = o_row;
                for (int lg = 0; lg < 32; ++lg) {
                    int np = s_npush[r][lg];
                    for (int s = 0; s < np; ++s) {
                        uint2 c = cand[(r*32 + lg)*2 + s];
                        float v = __uint_as_float(c.x);
                        int idx = (int)c.y;
                        if (o_cnt < TOPK) {
                            s_topv[r][o_cnt] = v; s_topi[r][o_cnt] = idx;
                            if (o_cnt == 0 || !lex_better(v, idx, o_minv, o_minidx)) {
                                o_minv = v; o_minidx = idx; o_minpos = o_cnt;
                            }
                            ++o_cnt;
                        } else if (lex_better(v, idx, o_minv, o_minidx)) {
                            s_topv[r][o_minpos] = v; s_topi[r][o_minpos] = idx;
                            float mv = s_topv[r][0]; int mi = s_topi[r][0], mp = 0;
                            for (int q = 1; q < TOPK; ++q) {
                                float qv = s_topv[r][q];
                                int   qi = s_topi[r][q];
                                if (qv < mv || (qv == mv && qi > mi)) { mv = qv; mi = qi; mp = q; }
                            }
                            o_minv = mv; o_minidx = mi; o_minpos = mp;
                        }
                    }
                }
                s_rowmin[r] = (o_cnt < TOPK) ? -INFINITY : o_minv;
            }
            __syncthreads();
            if (!more) break;
            p ^= 1;
        }
    }
    __syncthreads();
    // write per-(row,chunk) top-50 candidates (UNSORTED)
    for (int e = tid; e < BT*TOPK; e += 256) {
        int row = e / TOPK, j = e % TOPK;
        size_t g = ((size_t)(rbase + row) * NCH + blockIdx.y) * TOPK + j;
        cv[g] = s_topv[row][j];
        ci[g] = s_topi[row][j];
    }
}

// K2: exact merge of 16 UNSORTED runs of 50 -> top-50, then loss / mean_sim.
__global__ __launch_bounds__(256)
void knn_merge(const float* __restrict__ cv, const int* __restrict__ ci,
               const int* __restrict__ labels, const int* __restrict__ anchor_label,
               float* __restrict__ out)
{
    const int M = NCH * TOPK;   // 800
    __shared__ float s_val[NCH*TOPK];
    __shared__ int   s_idx[NCH*TOPK];
    __shared__ float s_sv[NCH*TOPK];
    __shared__ int   s_si[NCH*TOPK];
    __shared__ float s_runmin[NCH];
    __shared__ float s_T;
    __shared__ int   s_ns;
    __shared__ float s_sum;
    __shared__ int   s_cnt;

    const int row = blockIdx.x;
    const int tid = threadIdx.x;

    if (tid == 0) { s_ns = 0; s_sum = 0.f; s_cnt = 0; }
    for (int e = tid; e < M; e += 256) {
        s_val[e] = cv[(size_t)row*M + e];
        s_idx[e] = ci[(size_t)row*M + e];
    }
    __syncthreads();
    if (tid < NCH) {
        float m = INFINITY;
        for (int q = 0; q < TOPK; ++q) m = fminf(m, s_val[tid*TOPK + q]);
        s_runmin[tid] = m;
    }
    __syncthreads();
    if (tid == 0) {
        // lower bound on global 50th: the best run has 50 values >= its own min
        float t = -INFINITY;
        for (int c = 0; c < NCH; ++c) t = fmaxf(t, s_runmin[c]);
        s_T = t;
    }
    __syncthreads();
    const float T = s_T;
    for (int e = tid; e < M; e += 256) {
        float v = s_val[e];
        if (v >= T) {
            int p = atomicAdd(&s_ns, 1);
            s_sv[p] = v; s_si[p] = s_idx[e];
        }
    }
    __syncthreads();
    const int ns = s_ns;             // >= 50 guaranteed
    const int mylab = labels[row];
    for (int s = tid; s < ns; s += 256) {
        float v = s_sv[s]; int id = s_si[s];
        int r = 0;
        for (int q = 0; q < ns; ++q) {
            float vq = s_sv[q];
            r += (vq > v) || (vq == v && s_si[q] < id);   // jax tie-break: smaller index wins
        }
        if (r < TOPK) {
            atomicAdd(&s_sum, v);
            if (anchor_label[id] == mylab) atomicAdd(&s_cnt, 1);
        }
    }
    __syncthreads();
    if (tid == 0) {
        float mlp = (float)s_cnt / (float)TOPK;   // never NaN; ref's NaN-scrub is a no-op here
        out[row]          = -mlp;                 // loss
        out[B_ROWS + row] = s_sum / (float)TOPK;  // mean_sim
    }
}

extern "C" void kernel_launch(void* const* d_in, const int* in_sizes, int n_in,
                              void* d_out, int out_size, void* d_ws, size_t ws_size,
                              hipStream_t stream)
{
    const float* feat         = (const float*)d_in[0];
    const float* anc          = (const float*)d_in[1];
    const int*   labels       = (const int*)d_in[2];
    // d_in[3] = t_labels (unused by reference)
    const int*   anchor_label = (const int*)d_in[4];
    float* out = (float*)d_out;

    float* cv = (float*)d_ws;                                                   // 2048*800 fp32
    int*   ci = (int*)((char*)d_ws + (size_t)B_ROWS*NCH*TOPK*sizeof(float));    // 2048*800 i32

    hipLaunchKernelGGL(knn_chunk_topk, dim3(B_ROWS/BT, NCH), dim3(256), 0, stream,
                       feat, anc, cv, ci);
    hipLaunchKernelGGL(knn_merge, dim3(B_ROWS), dim3(256), 0, stream,
                       cv, ci, labels, anchor_label, out);
}

// Round 4
// 2805.692 us; speedup vs baseline: 5.3785x; 1.6627x over previous
//
#include <hip/hip_runtime.h>
#include <math.h>

// Problem constants (match setup_inputs)
#define B_ROWS 2048
#define N_ANCH 50000
#define DIM    256
#define TOPK   50

// K1 tiling
#define BT 64          // feature rows per block
#define AT 256         // anchors per tile
#define KC 32          // K chunk staged in LDS
#define NCH 16         // anchor chunks (50000/16 = 3125 exactly)
#define CHUNK 3125
#define NTILES 13      // ceil(3125/256)

#define SU_STRIDE 260  // anchor tile LDS row stride (floats); 1040 B keeps 16B align
#define SF_STRIDE 68   // feat tile LDS row stride
#define CAP 64         // candidate slots per row per round (64*8B*64 rows = 32 KB, fits sU)

__device__ __forceinline__ bool lex_better(float v1, int i1, float v2, int i2) {
    // "better" = ranked higher by jax top_k: larger value, ties -> smaller index
    return (v1 > v2) || (v1 == v2 && i1 < i2);
}

// K1: fused tiled fp32 GEMM + exact per-(row,chunk) top-50 (unsorted set).
// 64x256 block tile, 256 threads, 8x8 micro-tile, register-prefetch staging,
// atomic dense candidate lists + 64 parallel replace-min owners.
__global__ __launch_bounds__(256, 2)
void knn_chunk_topk(const float* __restrict__ feat,
                    const float* __restrict__ anc,
                    float* __restrict__ cv,
                    int*   __restrict__ ci)
{
    __shared__ __align__(16) float sU[32*SU_STRIDE]; // anchors (GEMM) / cand buffer (select)
    __shared__ __align__(16) float sF[KC*SF_STRIDE]; // features, k-major
    __shared__ float s_topv[BT][TOPK];               // UNSORTED top-50 values
    __shared__ int   s_topi[BT][TOPK];
    __shared__ float s_rowmin[BT];                   // current 50th-best (-inf while filling)
    __shared__ int   s_pcnt[2][BT];                  // parity-buffered push counters
    __shared__ int   s_more[2];

    uint2* cand = (uint2*)sU;                        // [BT][CAP]

    const int tid = threadIdx.x;
    const int rg  = tid >> 5;      // 0..7  -> rows rg*8..rg*8+7
    const int ag  = tid & 31;      // 0..31 -> anchors {4ag..4ag+3} U {128+4ag..128+4ag+3}
    const int rbase = blockIdx.x * BT;
    const int cbase = blockIdx.y * CHUNK;
    const int sa = tid >> 3;       // staging: anchor/row base (0..31)
    const int k4 = tid & 7;        // staging: float4 index within K-chunk

    if (tid < BT) s_rowmin[tid] = -INFINITY;

    // owner state in registers; thread 4*r owns row r
    int   o_cnt = 0;
    float o_minv = 0.f;
    int   o_minidx = 0, o_minpos = 0;
    const int  o_row   = tid >> 2;
    const bool is_owner = (tid & 3) == 0;

    const float4* A4 = (const float4*)anc;
    const float4* F4 = (const float4*)feat;

    float4 pa[8], pf[2];
    // prologue: prefetch tile 0, kc 0
    {
        #pragma unroll
        for (int it = 0; it < 8; ++it) {
            int ga = cbase + sa + 32*it; if (ga >= N_ANCH) ga = N_ANCH - 1;
            pa[it] = A4[(size_t)ga*(DIM/4) + k4];
        }
        #pragma unroll
        for (int it = 0; it < 2; ++it)
            pf[it] = F4[(size_t)(rbase + sa + 32*it)*(DIM/4) + k4];
    }

    for (int tile = 0; tile < NTILES; ++tile) {
        const int abase = cbase + tile * AT;
        const int valid = min(AT, cbase + CHUNK - abase);   // tail tile: 53

        float acc[8][8];
        #pragma unroll
        for (int i = 0; i < 8; ++i)
            #pragma unroll
            for (int j = 0; j < 8; ++j) acc[i][j] = 0.f;

        for (int kc = 0; kc < DIM/KC; ++kc) {
            __syncthreads();   // prev readers of sU/sF done
            // store prefetched regs -> LDS (transposed, k-major)
            #pragma unroll
            for (int it = 0; it < 8; ++it) {
                int a = sa + 32*it;
                sU[(k4*4+0)*SU_STRIDE + a] = pa[it].x;
                sU[(k4*4+1)*SU_STRIDE + a] = pa[it].y;
                sU[(k4*4+2)*SU_STRIDE + a] = pa[it].z;
                sU[(k4*4+3)*SU_STRIDE + a] = pa[it].w;
            }
            #pragma unroll
            for (int it = 0; it < 2; ++it) {
                int r = sa + 32*it;
                sF[(k4*4+0)*SF_STRIDE + r] = pf[it].x;
                sF[(k4*4+1)*SF_STRIDE + r] = pf[it].y;
                sF[(k4*4+2)*SF_STRIDE + r] = pf[it].z;
                sF[(k4*4+3)*SF_STRIDE + r] = pf[it].w;
            }
            __syncthreads();
            // prefetch next chunk: latency hidden behind the compute below
            if (kc < DIM/KC - 1) {
                #pragma unroll
                for (int it = 0; it < 8; ++it) {
                    int ga = abase + sa + 32*it; if (ga >= N_ANCH) ga = N_ANCH - 1;
                    pa[it] = A4[(size_t)ga*(DIM/4) + (kc+1)*8 + k4];
                }
                #pragma unroll
                for (int it = 0; it < 2; ++it)
                    pf[it] = F4[(size_t)(rbase + sa + 32*it)*(DIM/4) + (kc+1)*8 + k4];
            } else if (tile + 1 < NTILES) {
                const int nb = abase + AT;
                #pragma unroll
                for (int it = 0; it < 8; ++it) {
                    int ga = nb + sa + 32*it; if (ga >= N_ANCH) ga = N_ANCH - 1;
                    pa[it] = A4[(size_t)ga*(DIM/4) + k4];
                }
                #pragma unroll
                for (int it = 0; it < 2; ++it)
                    pf[it] = F4[(size_t)(rbase + sa + 32*it)*(DIM/4) + k4];
            }
            // compute
            #pragma unroll 4
            for (int k = 0; k < KC; ++k) {
                float4 f0 = *(const float4*)&sF[k*SF_STRIDE + rg*8];
                float4 f1 = *(const float4*)&sF[k*SF_STRIDE + rg*8 + 4];
                float4 a0 = *(const float4*)&sU[k*SU_STRIDE + 4*ag];
                float4 a1 = *(const float4*)&sU[k*SU_STRIDE + 128 + 4*ag];
                float fr[8] = {f0.x,f0.y,f0.z,f0.w,f1.x,f1.y,f1.z,f1.w};
                float ar[8] = {a0.x,a0.y,a0.z,a0.w,a1.x,a1.y,a1.z,a1.w};
                #pragma unroll
                for (int i = 0; i < 8; ++i)
                    #pragma unroll
                    for (int j = 0; j < 8; ++j)
                        acc[i][j] = fmaf(fr[i], ar[j], acc[i][j]);
            }
        }

        // ---- candidate selection (cand buffer aliases sU) ----
        if (tid < BT) s_pcnt[0][tid] = 0;
        if (tid == 0) s_more[0] = 0;
        __syncthreads();   // GEMM reads of sU done; resets visible

        unsigned rmask[8];
        #pragma unroll
        for (int i = 0; i < 8; ++i) rmask[i] = 0xFFu;

        int p = 0;
        for (int round = 0; round < 8; ++round) {
            // push phase: atomic slot grab into dense per-row list
            #pragma unroll
            for (int i = 0; i < 8; ++i) {
                unsigned m = rmask[i];
                if (!m) continue;
                const int r = rg*8 + i;
                const float rmv = s_rowmin[r];
                #pragma unroll
                for (int j = 0; j < 8; ++j) {
                    if (m & (1u<<j)) {
                        const int aoff = (j < 4) ? (4*ag + j) : (124 + 4*ag + j);
                        const float v = acc[i][j];
                        if (aoff < valid && v >= rmv) {
                            int slot = atomicAdd(&s_pcnt[p][r], 1);
                            if (slot < CAP) {
                                cand[r*CAP + slot] =
                                    make_uint2(__float_as_uint(v), (unsigned)(abase + aoff));
                                m &= ~(1u<<j);
                            } else {
                                s_more[p] = 1;      // deferred; retry next round
                            }
                        } else {
                            m &= ~(1u<<j);          // rejected (rowmin only rises) or OOB
                        }
                    }
                }
                rmask[i] = m;
            }
            if (tid < BT) s_pcnt[p^1][tid] = 0;
            if (tid == 0) s_more[p^1] = 0;
            __syncthreads();
            const int more = s_more[p];              // uniform between barriers
            // owner phase: 64 owners (16/wave), replace-min, fixed-50 rescan
            if (is_owner) {
                const int r = o_row;
                int cnt = s_pcnt[p][r]; if (cnt > CAP) cnt = CAP;
                for (int s = 0; s < cnt; ++s) {
                    uint2 c = cand[r*CAP + s];
                    float v = __uint_as_float(c.x);
                    int idx = (int)c.y;
                    if (o_cnt < TOPK) {
                        s_topv[r][o_cnt] = v; s_topi[r][o_cnt] = idx;
                        if (o_cnt == 0 || !lex_better(v, idx, o_minv, o_minidx)) {
                            o_minv = v; o_minidx = idx; o_minpos = o_cnt;
                        }
                        ++o_cnt;
                    } else if (lex_better(v, idx, o_minv, o_minidx)) {
                        s_topv[r][o_minpos] = v; s_topi[r][o_minpos] = idx;
                        float mv = s_topv[r][0]; int mi = s_topi[r][0], mp = 0;
                        for (int q = 1; q < TOPK; ++q) {
                            float qv = s_topv[r][q];
                            int   qi = s_topi[r][q];
                            if (qv < mv || (qv == mv && qi > mi)) { mv = qv; mi = qi; mp = q; }
                        }
                        o_minv = mv; o_minidx = mi; o_minpos = mp;
                    }
                }
                s_rowmin[r] = (o_cnt < TOPK) ? -INFINITY : o_minv;
            }
            __syncthreads();
            if (!more) break;
            p ^= 1;
        }
    }
    __syncthreads();
    // write per-(row,chunk) top-50 candidates (UNSORTED)
    for (int e = tid; e < BT*TOPK; e += 256) {
        int row = e / TOPK, j = e % TOPK;
        size_t g = ((size_t)(rbase + row) * NCH + blockIdx.y) * TOPK + j;
        cv[g] = s_topv[row][j];
        ci[g] = s_topi[row][j];
    }
}

// K2: exact merge of 16 UNSORTED runs of 50 -> top-50, then loss / mean_sim.
__global__ __launch_bounds__(256)
void knn_merge(const float* __restrict__ cv, const int* __restrict__ ci,
               const int* __restrict__ labels, const int* __restrict__ anchor_label,
               float* __restrict__ out)
{
    const int M = NCH * TOPK;   // 800
    __shared__ float s_val[NCH*TOPK];
    __shared__ int   s_idx[NCH*TOPK];
    __shared__ float s_sv[NCH*TOPK];
    __shared__ int   s_si[NCH*TOPK];
    __shared__ float s_runmin[NCH];
    __shared__ float s_T;
    __shared__ int   s_ns;
    __shared__ float s_sum;
    __shared__ int   s_cnt;

    const int row = blockIdx.x;
    const int tid = threadIdx.x;

    if (tid == 0) { s_ns = 0; s_sum = 0.f; s_cnt = 0; }
    for (int e = tid; e < M; e += 256) {
        s_val[e] = cv[(size_t)row*M + e];
        s_idx[e] = ci[(size_t)row*M + e];
    }
    __syncthreads();
    if (tid < NCH) {
        float m = INFINITY;
        for (int q = 0; q < TOPK; ++q) m = fminf(m, s_val[tid*TOPK + q]);
        s_runmin[tid] = m;
    }
    __syncthreads();
    if (tid == 0) {
        // lower bound on global 50th: the best run has 50 values >= its own min
        float t = -INFINITY;
        for (int c = 0; c < NCH; ++c) t = fmaxf(t, s_runmin[c]);
        s_T = t;
    }
    __syncthreads();
    const float T = s_T;
    for (int e = tid; e < M; e += 256) {
        float v = s_val[e];
        if (v >= T) {
            int p = atomicAdd(&s_ns, 1);
            s_sv[p] = v; s_si[p] = s_idx[e];
        }
    }
    __syncthreads();
    const int ns = s_ns;             // >= 50 guaranteed
    const int mylab = labels[row];
    for (int s = tid; s < ns; s += 256) {
        float v = s_sv[s]; int id = s_si[s];
        int r = 0;
        for (int q = 0; q < ns; ++q) {
            float vq = s_sv[q];
            r += (vq > v) || (vq == v && s_si[q] < id);   // jax tie-break: smaller index wins
        }
        if (r < TOPK) {
            atomicAdd(&s_sum, v);
            if (anchor_label[id] == mylab) atomicAdd(&s_cnt, 1);
        }
    }
    __syncthreads();
    if (tid == 0) {
        float mlp = (float)s_cnt / (float)TOPK;   // never NaN; ref's NaN-scrub is a no-op here
        out[row]          = -mlp;                 // loss
        out[B_ROWS + row] = s_sum / (float)TOPK;  // mean_sim
    }
}

extern "C" void kernel_launch(void* const* d_in, const int* in_sizes, int n_in,
                              void* d_out, int out_size, void* d_ws, size_t ws_size,
                              hipStream_t stream)
{
    const float* feat         = (const float*)d_in[0];
    const float* anc          = (const float*)d_in[1];
    const int*   labels       = (const int*)d_in[2];
    // d_in[3] = t_labels (unused by reference)
    const int*   anchor_label = (const int*)d_in[4];
    float* out = (float*)d_out;

    float* cv = (float*)d_ws;                                                   // 2048*800 fp32
    int*   ci = (int*)((char*)d_ws + (size_t)B_ROWS*NCH*TOPK*sizeof(float));    // 2048*800 i32

    hipLaunchKernelGGL(knn_chunk_topk, dim3(B_ROWS/BT, NCH), dim3(256), 0, stream,
                       feat, anc, cv, ci);
    hipLaunchKernelGGL(knn_merge, dim3(B_ROWS), dim3(256), 0, stream,
                       cv, ci, labels, anchor_label, out);
}

// Round 5
// 2389.294 us; speedup vs baseline: 6.3158x; 1.1743x over previous
//
#include <hip/hip_runtime.h>
#include <math.h>

// Problem constants (match setup_inputs)
#define B_ROWS 2048
#define N_ANCH 50000
#define DIM    256
#define TOPK   50

// K1 tiling
#define BT 64          // feature rows per block
#define AT 256         // anchors per tile (4 waves x 64)
#define KC 32          // k per staged chunk (= one MFMA K)
#define NCHUNK 8       // DIM/KC
#define NCH 16         // anchor chunks (50000/16 = 3125)
#define CHUNK 3125
#define NTILES 13      // ceil(3125/256)
#define CAP 64         // candidate slots per row per round

typedef __attribute__((ext_vector_type(8))) short bf16x8;   // 8 bf16 in 4 VGPRs
typedef __attribute__((ext_vector_type(4))) float f32x4;

// LDS byte offsets inside sMem (40 KB)
#define OFF_BHI 0          // anchors hi: slot = kq*256 + a, 16B/slot -> 16 KB
#define OFF_BLO 16384      // anchors lo: 16 KB
#define OFF_AHI 32768      // feats hi:   slot = kq*64 + r -> 4 KB
#define OFF_ALO 36864      // feats lo:   4 KB
#define SMEM_BYTES 40960

__device__ __forceinline__ void gl_lds16(const void* g, void* l) {
    // async global->LDS, 16B/lane; LDS dest = uniform base + lane*16
    __builtin_amdgcn_global_load_lds(
        (const __attribute__((address_space(1))) unsigned int*)g,
        (__attribute__((address_space(3))) unsigned int*)l, 16, 0, 0);
}

__device__ __forceinline__ bool lex_better(float v1, int i1, float v2, int i2) {
    return (v1 > v2) || (v1 == v2 && i1 < i2);   // jax top_k order
}

__device__ __forceinline__ unsigned short f2bf(float x) {
    unsigned u = __float_as_uint(x);
    u += 0x7FFFu + ((u >> 16) & 1u);             // RNE
    return (unsigned short)(u >> 16);
}

// K0: split fp32 -> bf16 hi + bf16 lo (x ~= hi + lo to ~2^-17 rel)
__global__ void split_bf16(const float* __restrict__ x,
                           unsigned short* __restrict__ hi,
                           unsigned short* __restrict__ lo, int n4)
{
    int i = blockIdx.x * blockDim.x + threadIdx.x;
    const int stride = gridDim.x * blockDim.x;
    const float4* X4 = (const float4*)x;
    for (; i < n4; i += stride) {
        float4 v = X4[i];
        ushort4 h, l;
        float f;
        h.x = f2bf(v.x); f = v.x - __uint_as_float((unsigned)h.x << 16); l.x = f2bf(f);
        h.y = f2bf(v.y); f = v.y - __uint_as_float((unsigned)h.y << 16); l.y = f2bf(f);
        h.z = f2bf(v.z); f = v.z - __uint_as_float((unsigned)h.z << 16); l.z = f2bf(f);
        h.w = f2bf(v.w); f = v.w - __uint_as_float((unsigned)h.w << 16); l.w = f2bf(f);
        ((ushort4*)hi)[i] = h;
        ((ushort4*)lo)[i] = l;
    }
}

// K1: 3-pass bf16 MFMA GEMM (exact to ~1e-4) + exact per-(row,chunk) top-50.
// 64x256 block tile, 4 waves; wave w owns anchors [64w,64w+64): 4x4 subtiles 16x16.
__global__ __launch_bounds__(256, 2)
void knn_mfma_topk(const unsigned short* __restrict__ fhi,
                   const unsigned short* __restrict__ flo,
                   const unsigned short* __restrict__ ahi,
                   const unsigned short* __restrict__ alo,
                   float* __restrict__ cv, int* __restrict__ ci)
{
    __shared__ __align__(16) unsigned char sMem[SMEM_BYTES];
    __shared__ float s_topv[BT][TOPK];               // UNSORTED top-50
    __shared__ int   s_topi[BT][TOPK];
    __shared__ float s_rowmin[BT];                   // current 50th-best
    __shared__ int   s_pcnt[2][BT];
    __shared__ int   s_more[2];

    uint2* cand = (uint2*)sMem;                      // 32 KB alias of B buffers (dead in selection)

    const int tid  = threadIdx.x;
    const int w    = tid >> 6;        // wave 0..3
    const int lane = tid & 63;
    const int quad = lane >> 4;
    const int lx   = lane & 15;
    const int rbase = blockIdx.x * BT;
    const int cbase = blockIdx.y * CHUNK;

    if (tid < BT) s_rowmin[tid] = -INFINITY;

    // owner state in registers; thread 4*r owns row r
    int   o_cnt = 0;
    float o_minv = 0.f;
    int   o_minidx = 0, o_minpos = 0;
    const int  o_row   = tid >> 2;
    const bool is_owner = (tid & 3) == 0;

    const int tB = w * 4;                            // B staging instr ids for this wave
    const int frow = rbase + lane;                   // A staging row (instr t=w, kq=w)

    for (int tile = 0; tile < NTILES; ++tile) {
        const int abase = cbase + tile * AT;
        const int valid = min(AT, cbase + CHUNK - abase);   // tail tile: 53

        // clamped anchor rows for this wave's 4 B staging instrs
        int garow[4];
        #pragma unroll
        for (int i = 0; i < 4; ++i) {
            int t = tB + i;
            int a = ((t & 3) << 6) + lane;           // slot = t*64+lane -> a = (t&3)*64+lane
            int g = abase + a; if (g > N_ANCH - 1) g = N_ANCH - 1;
            garow[i] = g;
        }

        f32x4 acc[4][4];
        const f32x4 z = {0.f, 0.f, 0.f, 0.f};
        #pragma unroll
        for (int tm = 0; tm < 4; ++tm)
            #pragma unroll
            for (int tn = 0; tn < 4; ++tn) acc[tm][tn] = z;

        for (int c = 0; c < NCHUNK; ++c) {
            __syncthreads();        // prev chunk frag reads / prev selection done
            const int kb = c * KC;
            // stage anchors: slot = kq*256 + a  (kq = t>>2), 16B/slot
            #pragma unroll
            for (int i = 0; i < 4; ++i) {
                int t = tB + i;
                size_t goff = (size_t)garow[i] * DIM + kb + ((t >> 2) << 3);
                gl_lds16(ahi + goff, sMem + OFF_BHI + t * 1024);
                gl_lds16(alo + goff, sMem + OFF_BLO + t * 1024);
            }
            // stage feats: slot = kq*64 + r (kq = w), one hi + one lo instr per wave
            {
                size_t goff = (size_t)frow * DIM + kb + (w << 3);
                gl_lds16(fhi + goff, sMem + OFF_AHI + w * 1024);
                gl_lds16(flo + goff, sMem + OFF_ALO + w * 1024);
            }
            __syncthreads();        // vmcnt drained by compiler before barrier

            // fragments: lane holds [idx = lane&15][k = quad*8 + j]
            bf16x8 bh[4], bl[4], ah[4], al[4];
            #pragma unroll
            for (int tn = 0; tn < 4; ++tn) {
                int a = (w << 6) + (tn << 4) + lx;
                int off = (quad << 12) + (a << 4);      // (kq*256 + a)*16
                bh[tn] = *(const bf16x8*)(sMem + OFF_BHI + off);
                bl[tn] = *(const bf16x8*)(sMem + OFF_BLO + off);
            }
            #pragma unroll
            for (int tm = 0; tm < 4; ++tm) {
                int r = (tm << 4) + lx;
                int off = (quad << 10) + (r << 4);      // (kq*64 + r)*16
                ah[tm] = *(const bf16x8*)(sMem + OFF_AHI + off);
                al[tm] = *(const bf16x8*)(sMem + OFF_ALO + off);
            }
            // 3-pass: A*B ~= Ah*Bh + Al*Bh + Ah*Bl  (drop Al*Bl ~ 2^-18)
            #pragma unroll
            for (int tm = 0; tm < 4; ++tm)
                #pragma unroll
                for (int tn = 0; tn < 4; ++tn) {
                    acc[tm][tn] = __builtin_amdgcn_mfma_f32_16x16x32_bf16(ah[tm], bh[tn], acc[tm][tn], 0, 0, 0);
                    acc[tm][tn] = __builtin_amdgcn_mfma_f32_16x16x32_bf16(al[tm], bh[tn], acc[tm][tn], 0, 0, 0);
                    acc[tm][tn] = __builtin_amdgcn_mfma_f32_16x16x32_bf16(ah[tm], bl[tn], acc[tm][tn], 0, 0, 0);
                }
        }

        // ---- candidate selection (cand aliases B buffers) ----
        // C/D layout: row m = quad*4 + reg (+16*tm), col n = lx (+16*tn, +64*w)
        if (tid < BT) s_pcnt[0][tid] = 0;
        if (tid == 0) s_more[0] = 0;
        __syncthreads();

        unsigned rmask[4];
        #pragma unroll
        for (int tm = 0; tm < 4; ++tm) rmask[tm] = 0xFFFFu;

        int p = 0;
        for (int round = 0; round < 8; ++round) {
            #pragma unroll
            for (int tm = 0; tm < 4; ++tm) {
                unsigned m = rmask[tm];
                if (!m) continue;
                #pragma unroll
                for (int tn = 0; tn < 4; ++tn) {
                    #pragma unroll
                    for (int reg = 0; reg < 4; ++reg) {
                        const unsigned bit = 1u << (tn * 4 + reg);
                        if (m & bit) {
                            const int   r    = (tm << 4) + (quad << 2) + reg;
                            const float rmv  = s_rowmin[r];
                            const int   aoff = (w << 6) + (tn << 4) + lx;
                            const float v    = acc[tm][tn][reg];
                            if (aoff < valid && v >= rmv) {
                                int slot = atomicAdd(&s_pcnt[p][r], 1);
                                if (slot < CAP) {
                                    cand[r * CAP + slot] =
                                        make_uint2(__float_as_uint(v), (unsigned)(abase + aoff));
                                    m &= ~bit;
                                } else {
                                    s_more[p] = 1;      // deferred; retry
                                }
                            } else {
                                m &= ~bit;              // rejected (rowmin only rises) or OOB
                            }
                        }
                    }
                }
                rmask[tm] = m;
            }
            if (tid < BT) s_pcnt[p ^ 1][tid] = 0;
            if (tid == 0) s_more[p ^ 1] = 0;
            __syncthreads();
            const int more = s_more[p];                  // uniform between barriers
            if (is_owner) {
                const int r = o_row;
                int cnt = s_pcnt[p][r]; if (cnt > CAP) cnt = CAP;
                for (int s = 0; s < cnt; ++s) {
                    uint2 cdat = cand[r * CAP + s];
                    float v = __uint_as_float(cdat.x);
                    int idx = (int)cdat.y;
                    if (o_cnt < TOPK) {
                        s_topv[r][o_cnt] = v; s_topi[r][o_cnt] = idx;
                        if (o_cnt == 0 || !lex_better(v, idx, o_minv, o_minidx)) {
                            o_minv = v; o_minidx = idx; o_minpos = o_cnt;
                        }
                        ++o_cnt;
                    } else if (lex_better(v, idx, o_minv, o_minidx)) {
                        s_topv[r][o_minpos] = v; s_topi[r][o_minpos] = idx;
                        float mv = s_topv[r][0]; int mi = s_topi[r][0], mp = 0;
                        for (int q = 1; q < TOPK; ++q) {
                            float qv = s_topv[r][q];
                            int   qi = s_topi[r][q];
                            if (qv < mv || (qv == mv && qi > mi)) { mv = qv; mi = qi; mp = q; }
                        }
                        o_minv = mv; o_minidx = mi; o_minpos = mp;
                    }
                }
                s_rowmin[r] = (o_cnt < TOPK) ? -INFINITY : o_minv;
            }
            __syncthreads();
            if (!more) break;
            p ^= 1;
        }
    }
    __syncthreads();
    // write per-(row,chunk) top-50 (UNSORTED)
    for (int e = tid; e < BT * TOPK; e += 256) {
        int row = e / TOPK, j = e % TOPK;
        size_t g = ((size_t)(rbase + row) * NCH + blockIdx.y) * TOPK + j;
        cv[g] = s_topv[row][j];
        ci[g] = s_topi[row][j];
    }
}

// K2: exact merge of 16 UNSORTED runs of 50 -> top-50, then loss / mean_sim.
__global__ __launch_bounds__(256)
void knn_merge(const float* __restrict__ cv, const int* __restrict__ ci,
               const int* __restrict__ labels, const int* __restrict__ anchor_label,
               float* __restrict__ out)
{
    const int M = NCH * TOPK;   // 800
    __shared__ float s_val[NCH*TOPK];
    __shared__ int   s_idx[NCH*TOPK];
    __shared__ float s_sv[NCH*TOPK];
    __shared__ int   s_si[NCH*TOPK];
    __shared__ float s_runmin[NCH];
    __shared__ float s_T;
    __shared__ int   s_ns;
    __shared__ float s_sum;
    __shared__ int   s_cnt;

    const int row = blockIdx.x;
    const int tid = threadIdx.x;

    if (tid == 0) { s_ns = 0; s_sum = 0.f; s_cnt = 0; }
    for (int e = tid; e < M; e += 256) {
        s_val[e] = cv[(size_t)row*M + e];
        s_idx[e] = ci[(size_t)row*M + e];
    }
    __syncthreads();
    if (tid < NCH) {
        float m = INFINITY;
        for (int q = 0; q < TOPK; ++q) m = fminf(m, s_val[tid*TOPK + q]);
        s_runmin[tid] = m;
    }
    __syncthreads();
    if (tid == 0) {
        float t = -INFINITY;
        for (int c = 0; c < NCH; ++c) t = fmaxf(t, s_runmin[c]);
        s_T = t;   // lower bound on global 50th
    }
    __syncthreads();
    const float T = s_T;
    for (int e = tid; e < M; e += 256) {
        float v = s_val[e];
        if (v >= T) {
            int p = atomicAdd(&s_ns, 1);
            s_sv[p] = v; s_si[p] = s_idx[e];
        }
    }
    __syncthreads();
    const int ns = s_ns;             // >= 50 guaranteed
    const int mylab = labels[row];
    for (int s = tid; s < ns; s += 256) {
        float v = s_sv[s]; int id = s_si[s];
        int r = 0;
        for (int q = 0; q < ns; ++q) {
            float vq = s_sv[q];
            r += (vq > v) || (vq == v && s_si[q] < id);   // smaller index wins ties
        }
        if (r < TOPK) {
            atomicAdd(&s_sum, v);
            if (anchor_label[id] == mylab) atomicAdd(&s_cnt, 1);
        }
    }
    __syncthreads();
    if (tid == 0) {
        float mlp = (float)s_cnt / (float)TOPK;
        out[row]          = -mlp;                 // loss
        out[B_ROWS + row] = s_sum / (float)TOPK;  // mean_sim
    }
}

extern "C" void kernel_launch(void* const* d_in, const int* in_sizes, int n_in,
                              void* d_out, int out_size, void* d_ws, size_t ws_size,
                              hipStream_t stream)
{
    const float* feat         = (const float*)d_in[0];
    const float* anc          = (const float*)d_in[1];
    const int*   labels       = (const int*)d_in[2];
    // d_in[3] = t_labels (unused)
    const int*   anchor_label = (const int*)d_in[4];
    float* out = (float*)d_out;

    char* ws = (char*)d_ws;
    size_t off = 0;
    float* cv = (float*)(ws + off);          off += (size_t)B_ROWS * NCH * TOPK * 4;   // 6.55 MB
    int*   ci = (int*)(ws + off);            off += (size_t)B_ROWS * NCH * TOPK * 4;   // 6.55 MB
    unsigned short* fhi = (unsigned short*)(ws + off); off += (size_t)B_ROWS * DIM * 2; // 1.05 MB
    unsigned short* flo = (unsigned short*)(ws + off); off += (size_t)B_ROWS * DIM * 2;
    unsigned short* ahi = (unsigned short*)(ws + off); off += (size_t)N_ANCH * DIM * 2; // 25.6 MB
    unsigned short* alo = (unsigned short*)(ws + off);                                  // 25.6 MB

    hipLaunchKernelGGL(split_bf16, dim3(256), dim3(256), 0, stream,
                       feat, fhi, flo, B_ROWS * DIM / 4);
    hipLaunchKernelGGL(split_bf16, dim3(4096), dim3(256), 0, stream,
                       anc, ahi, alo, N_ANCH * DIM / 4);
    hipLaunchKernelGGL(knn_mfma_topk, dim3(B_ROWS / BT, NCH), dim3(256), 0, stream,
                       fhi, flo, ahi, alo, cv, ci);
    hipLaunchKernelGGL(knn_merge, dim3(B_ROWS), dim3(256), 0, stream,
                       cv, ci, labels, anchor_label, out);
}

// Round 6
// 1892.815 us; speedup vs baseline: 7.9725x; 1.2623x over previous
//
#include <hip/hip_runtime.h>
#include <math.h>

// Problem constants (match setup_inputs)
#define B_ROWS 2048
#define N_ANCH 50000
#define DIM    256
#define TOPK   50

// K1 tiling
#define BT 64          // feature rows per block
#define AT 256         // anchors per tile (4 waves x 64)
#define KC 32          // k per staged chunk (= one MFMA K)
#define NCHUNK 8       // DIM/KC
#define NCH 16         // anchor chunks (50000/16 = 3125)
#define CHUNK 3125
#define NTILES 13      // ceil(3125/256)
#define CAP 64         // candidate slots per row per round

typedef __attribute__((ext_vector_type(8))) short bf16x8;   // 8 bf16 in 4 VGPRs
typedef __attribute__((ext_vector_type(4))) float f32x4;

// LDS byte offsets inside sMem (40 KB)
#define OFF_BHI 0          // anchors hi: slot = kq*256 + a, 16B/slot -> 16 KB
#define OFF_BLO 16384      // anchors lo: 16 KB
#define OFF_AHI 32768      // feats hi:   slot = kq*64 + r -> 4 KB
#define OFF_ALO 36864      // feats lo:   4 KB
#define SMEM_BYTES 40960

__device__ __forceinline__ void gl_lds16(const void* g, void* l) {
    // async global->LDS, 16B/lane; LDS dest = uniform base + lane*16
    __builtin_amdgcn_global_load_lds(
        (const __attribute__((address_space(1))) unsigned int*)g,
        (__attribute__((address_space(3))) unsigned int*)l, 16, 0, 0);
}

__device__ __forceinline__ unsigned short f2bf(float x) {
    unsigned u = __float_as_uint(x);
    u += 0x7FFFu + ((u >> 16) & 1u);             // RNE
    return (unsigned short)(u >> 16);
}

// K0: split fp32 -> bf16 hi + bf16 lo (x ~= hi + lo to ~2^-17 rel)
__global__ void split_bf16(const float* __restrict__ x,
                           unsigned short* __restrict__ hi,
                           unsigned short* __restrict__ lo, int n4)
{
    int i = blockIdx.x * blockDim.x + threadIdx.x;
    const int stride = gridDim.x * blockDim.x;
    const float4* X4 = (const float4*)x;
    for (; i < n4; i += stride) {
        float4 v = X4[i];
        ushort4 h, l;
        float f;
        h.x = f2bf(v.x); f = v.x - __uint_as_float((unsigned)h.x << 16); l.x = f2bf(f);
        h.y = f2bf(v.y); f = v.y - __uint_as_float((unsigned)h.y << 16); l.y = f2bf(f);
        h.z = f2bf(v.z); f = v.z - __uint_as_float((unsigned)h.z << 16); l.z = f2bf(f);
        h.w = f2bf(v.w); f = v.w - __uint_as_float((unsigned)h.w << 16); l.w = f2bf(f);
        ((ushort4*)hi)[i] = h;
        ((ushort4*)lo)[i] = l;
    }
}

// K1: 3-pass bf16 MFMA GEMM (exact to ~1e-4) + exact per-(row,chunk) top-50.
// 64x256 block tile, 4 waves; wave w owns anchors [64w,64w+64): 4x4 subtiles 16x16.
// Selection: atomic candidate lists + wave-cooperative rank-merge (64 lanes/row).
__global__ __launch_bounds__(256, 2)
void knn_mfma_topk(const unsigned short* __restrict__ fhi,
                   const unsigned short* __restrict__ flo,
                   const unsigned short* __restrict__ ahi,
                   const unsigned short* __restrict__ alo,
                   float* __restrict__ cv, int* __restrict__ ci)
{
    __shared__ __align__(16) unsigned char sMem[SMEM_BYTES];
    __shared__ uint2 s_top[BT][TOPK];                // SORTED top-50 (v desc, idx asc), packed
    __shared__ float s_rowmin[BT];                   // current 50th-best (-inf while filling)
    __shared__ int   s_cnt2[BT];                     // stored count (<= 50)
    __shared__ int   s_pcnt[2][BT];
    __shared__ int   s_more[2];

    uint2* cand = (uint2*)sMem;                      // 32 KB alias of B buffers (dead in selection)

    const int tid  = threadIdx.x;
    const int w    = tid >> 6;        // wave 0..3
    const int lane = tid & 63;
    const int quad = lane >> 4;
    const int lx   = lane & 15;
    const int rbase = blockIdx.x * BT;
    const int cbase = blockIdx.y * CHUNK;

    if (tid < BT) { s_rowmin[tid] = -INFINITY; s_cnt2[tid] = 0; }

    const int tB = w * 4;                            // B staging instr ids for this wave
    const int frow = rbase + lane;                   // A staging row

    for (int tile = 0; tile < NTILES; ++tile) {
        const int abase = cbase + tile * AT;
        const int valid = min(AT, cbase + CHUNK - abase);   // tail tile: 53

        // clamped anchor rows for this wave's 4 B staging instrs
        int garow[4];
        #pragma unroll
        for (int i = 0; i < 4; ++i) {
            int t = tB + i;
            int a = ((t & 3) << 6) + lane;           // slot = t*64+lane -> a = (t&3)*64+lane
            int g = abase + a; if (g > N_ANCH - 1) g = N_ANCH - 1;
            garow[i] = g;
        }

        f32x4 acc[4][4];
        const f32x4 z = {0.f, 0.f, 0.f, 0.f};
        #pragma unroll
        for (int tm = 0; tm < 4; ++tm)
            #pragma unroll
            for (int tn = 0; tn < 4; ++tn) acc[tm][tn] = z;

        for (int c = 0; c < NCHUNK; ++c) {
            __syncthreads();        // prev chunk frag reads / prev selection done
            const int kb = c * KC;
            // stage anchors: slot = kq*256 + a  (kq = t>>2), 16B/slot
            #pragma unroll
            for (int i = 0; i < 4; ++i) {
                int t = tB + i;
                size_t goff = (size_t)garow[i] * DIM + kb + ((t >> 2) << 3);
                gl_lds16(ahi + goff, sMem + OFF_BHI + t * 1024);
                gl_lds16(alo + goff, sMem + OFF_BLO + t * 1024);
            }
            // stage feats: slot = kq*64 + r (kq = w)
            {
                size_t goff = (size_t)frow * DIM + kb + (w << 3);
                gl_lds16(fhi + goff, sMem + OFF_AHI + w * 1024);
                gl_lds16(flo + goff, sMem + OFF_ALO + w * 1024);
            }
            __syncthreads();        // vmcnt drained by compiler before barrier

            // fragments: lane holds [idx = lane&15][k = quad*8 + j]
            bf16x8 bh[4], bl[4], ah[4], al[4];
            #pragma unroll
            for (int tn = 0; tn < 4; ++tn) {
                int a = (w << 6) + (tn << 4) + lx;
                int off = (quad << 12) + (a << 4);      // (kq*256 + a)*16
                bh[tn] = *(const bf16x8*)(sMem + OFF_BHI + off);
                bl[tn] = *(const bf16x8*)(sMem + OFF_BLO + off);
            }
            #pragma unroll
            for (int tm = 0; tm < 4; ++tm) {
                int r = (tm << 4) + lx;
                int off = (quad << 10) + (r << 4);      // (kq*64 + r)*16
                ah[tm] = *(const bf16x8*)(sMem + OFF_AHI + off);
                al[tm] = *(const bf16x8*)(sMem + OFF_ALO + off);
            }
            // 3-pass: A*B ~= Ah*Bh + Al*Bh + Ah*Bl  (drop Al*Bl ~ 2^-18)
            #pragma unroll
            for (int tm = 0; tm < 4; ++tm)
                #pragma unroll
                for (int tn = 0; tn < 4; ++tn) {
                    acc[tm][tn] = __builtin_amdgcn_mfma_f32_16x16x32_bf16(ah[tm], bh[tn], acc[tm][tn], 0, 0, 0);
                    acc[tm][tn] = __builtin_amdgcn_mfma_f32_16x16x32_bf16(al[tm], bh[tn], acc[tm][tn], 0, 0, 0);
                    acc[tm][tn] = __builtin_amdgcn_mfma_f32_16x16x32_bf16(ah[tm], bl[tn], acc[tm][tn], 0, 0, 0);
                }
        }

        // ---- candidate selection (cand aliases B buffers) ----
        // C/D layout: row m = quad*4 + reg (+16*tm), col n = lx (+16*tn, +64*w)
        if (tid < BT) s_pcnt[0][tid] = 0;
        if (tid == 0) s_more[0] = 0;
        __syncthreads();

        unsigned rmask[4];
        #pragma unroll
        for (int tm = 0; tm < 4; ++tm) rmask[tm] = 0xFFFFu;

        int p = 0;
        for (int round = 0; round < 8; ++round) {
            // push phase: atomic slot grab into dense per-row list
            #pragma unroll
            for (int tm = 0; tm < 4; ++tm) {
                unsigned m = rmask[tm];
                if (!m) continue;
                #pragma unroll
                for (int tn = 0; tn < 4; ++tn) {
                    #pragma unroll
                    for (int reg = 0; reg < 4; ++reg) {
                        const unsigned bit = 1u << (tn * 4 + reg);
                        if (m & bit) {
                            const int   r    = (tm << 4) + (quad << 2) + reg;
                            const float rmv  = s_rowmin[r];
                            const int   aoff = (w << 6) + (tn << 4) + lx;
                            const float v    = acc[tm][tn][reg];
                            if (aoff < valid && v >= rmv) {
                                int slot = atomicAdd(&s_pcnt[p][r], 1);
                                if (slot < CAP) {
                                    cand[r * CAP + slot] =
                                        make_uint2(__float_as_uint(v), (unsigned)(abase + aoff));
                                    m &= ~bit;
                                } else {
                                    s_more[p] = 1;      // deferred; retry
                                }
                            } else {
                                m &= ~bit;              // rejected (rowmin only rises) or OOB
                            }
                        }
                    }
                }
                rmask[tm] = m;
            }
            if (tid < BT) s_pcnt[p ^ 1][tid] = 0;
            if (tid == 0) s_more[p ^ 1] = 0;
            __syncthreads();
            const int more = s_more[p];                  // uniform between barriers

            // wave-cooperative rank-merge: wave w handles rows 16w..16w+15
            for (int rr = 0; rr < 16; ++rr) {
                const int r = (w << 4) + rr;
                int cnt = s_pcnt[p][r]; if (cnt > CAP) cnt = CAP;
                if (cnt == 0) continue;                  // wave-uniform
                const int k0   = s_cnt2[r];
                const int pool = k0 + cnt;               // <= 114
                // my pool elements: e0 = lane, e1 = lane + 64
                const int e0 = lane, e1 = lane + 64;
                const bool h0 = e0 < pool, h1 = e1 < pool;
                float v0 = 0.f, v1 = 0.f; int i0 = 0, i1 = 0;
                if (h0) { uint2 cc = (e0 < k0) ? s_top[r][e0] : cand[r*CAP + (e0 - k0)];
                          v0 = __uint_as_float(cc.x); i0 = (int)cc.y; }
                if (h1) { uint2 cc = (e1 < k0) ? s_top[r][e1] : cand[r*CAP + (e1 - k0)];
                          v1 = __uint_as_float(cc.x); i1 = (int)cc.y; }
                // exact lex-rank (v desc, idx asc) vs whole pool (broadcast reads)
                int r0 = 0, r1 = 0;
                for (int q = 0; q < k0; ++q) {
                    uint2 cc = s_top[r][q];
                    float vq = __uint_as_float(cc.x); int iq = (int)cc.y;
                    r0 += (vq > v0) || (vq == v0 && iq < i0);
                    r1 += (vq > v1) || (vq == v1 && iq < i1);
                }
                for (int q = 0; q < cnt; ++q) {
                    uint2 cc = cand[r*CAP + q];
                    float vq = __uint_as_float(cc.x); int iq = (int)cc.y;
                    r0 += (vq > v0) || (vq == v0 && iq < i0);
                    r1 += (vq > v1) || (vq == v1 && iq < i1);
                }
                // writes issue after all lanes' rank loops (wave lockstep); ranks unique
                if (h0 && r0 < TOPK) s_top[r][r0] = make_uint2(__float_as_uint(v0), (unsigned)i0);
                if (h1 && r1 < TOPK) s_top[r][r1] = make_uint2(__float_as_uint(v1), (unsigned)i1);
                if (h0 && r0 == TOPK-1) s_rowmin[r] = v0;    // pool>=50 iff some rank==49
                if (h1 && r1 == TOPK-1) s_rowmin[r] = v1;
                if (lane == 0) s_cnt2[r] = (pool < TOPK) ? pool : TOPK;
            }
            __syncthreads();
            if (!more) break;
            p ^= 1;
        }
    }
    __syncthreads();
    // write per-(row,chunk) top-50 (sorted, but K2 treats as unordered set)
    for (int e = tid; e < BT * TOPK; e += 256) {
        int row = e / TOPK, j = e % TOPK;
        uint2 cc = s_top[row][j];
        size_t g = ((size_t)(rbase + row) * NCH + blockIdx.y) * TOPK + j;
        cv[g] = __uint_as_float(cc.x);
        ci[g] = (int)cc.y;
    }
}

// K2: exact merge of 16 runs of 50 -> top-50, then loss / mean_sim.
__global__ __launch_bounds__(256)
void knn_merge(const float* __restrict__ cv, const int* __restrict__ ci,
               const int* __restrict__ labels, const int* __restrict__ anchor_label,
               float* __restrict__ out)
{
    const int M = NCH * TOPK;   // 800
    __shared__ float s_val[NCH*TOPK];
    __shared__ int   s_idx[NCH*TOPK];
    __shared__ float s_sv[NCH*TOPK];
    __shared__ int   s_si[NCH*TOPK];
    __shared__ float s_runmin[NCH];
    __shared__ float s_T;
    __shared__ int   s_ns;
    __shared__ float s_sum;
    __shared__ int   s_cnt;

    const int row = blockIdx.x;
    const int tid = threadIdx.x;

    if (tid == 0) { s_ns = 0; s_sum = 0.f; s_cnt = 0; }
    for (int e = tid; e < M; e += 256) {
        s_val[e] = cv[(size_t)row*M + e];
        s_idx[e] = ci[(size_t)row*M + e];
    }
    __syncthreads();
    if (tid < NCH) {
        float m = INFINITY;
        for (int q = 0; q < TOPK; ++q) m = fminf(m, s_val[tid*TOPK + q]);
        s_runmin[tid] = m;
    }
    __syncthreads();
    if (tid == 0) {
        float t = -INFINITY;
        for (int c = 0; c < NCH; ++c) t = fmaxf(t, s_runmin[c]);
        s_T = t;   // lower bound on global 50th
    }
    __syncthreads();
    const float T = s_T;
    for (int e = tid; e < M; e += 256) {
        float v = s_val[e];
        if (v >= T) {
            int p = atomicAdd(&s_ns, 1);
            s_sv[p] = v; s_si[p] = s_idx[e];
        }
    }
    __syncthreads();
    const int ns = s_ns;             // >= 50 guaranteed
    const int mylab = labels[row];
    for (int s = tid; s < ns; s += 256) {
        float v = s_sv[s]; int id = s_si[s];
        int r = 0;
        for (int q = 0; q < ns; ++q) {
            float vq = s_sv[q];
            r += (vq > v) || (vq == v && s_si[q] < id);   // smaller index wins ties
        }
        if (r < TOPK) {
            atomicAdd(&s_sum, v);
            if (anchor_label[id] == mylab) atomicAdd(&s_cnt, 1);
        }
    }
    __syncthreads();
    if (tid == 0) {
        float mlp = (float)s_cnt / (float)TOPK;
        out[row]          = -mlp;                 // loss
        out[B_ROWS + row] = s_sum / (float)TOPK;  // mean_sim
    }
}

extern "C" void kernel_launch(void* const* d_in, const int* in_sizes, int n_in,
                              void* d_out, int out_size, void* d_ws, size_t ws_size,
                              hipStream_t stream)
{
    const float* feat         = (const float*)d_in[0];
    const float* anc          = (const float*)d_in[1];
    const int*   labels       = (const int*)d_in[2];
    // d_in[3] = t_labels (unused)
    const int*   anchor_label = (const int*)d_in[4];
    float* out = (float*)d_out;

    char* ws = (char*)d_ws;
    size_t off = 0;
    float* cv = (float*)(ws + off);          off += (size_t)B_ROWS * NCH * TOPK * 4;   // 6.55 MB
    int*   ci = (int*)(ws + off);            off += (size_t)B_ROWS * NCH * TOPK * 4;   // 6.55 MB
    unsigned short* fhi = (unsigned short*)(ws + off); off += (size_t)B_ROWS * DIM * 2; // 1.05 MB
    unsigned short* flo = (unsigned short*)(ws + off); off += (size_t)B_ROWS * DIM * 2;
    unsigned short* ahi = (unsigned short*)(ws + off); off += (size_t)N_ANCH * DIM * 2; // 25.6 MB
    unsigned short* alo = (unsigned short*)(ws + off);                                  // 25.6 MB

    hipLaunchKernelGGL(split_bf16, dim3(256), dim3(256), 0, stream,
                       feat, fhi, flo, B_ROWS * DIM / 4);
    hipLaunchKernelGGL(split_bf16, dim3(4096), dim3(256), 0, stream,
                       anc, ahi, alo, N_ANCH * DIM / 4);
    hipLaunchKernelGGL(knn_mfma_topk, dim3(B_ROWS / BT, NCH), dim3(256), 0, stream,
                       fhi, flo, ahi, alo, cv, ci);
    hipLaunchKernelGGL(knn_merge, dim3(B_ROWS), dim3(256), 0, stream,
                       cv, ci, labels, anchor_label, out);
}

// Round 7
// 1567.029 us; speedup vs baseline: 9.6299x; 1.2079x over previous
//
#include <hip/hip_runtime.h>
#include <math.h>

// Problem constants (match setup_inputs)
#define B_ROWS 2048
#define N_ANCH 50000
#define DIM    256
#define TOPK   50

// K1 tiling
#define BT 64          // feature rows per block
#define AT 256         // anchors per tile (4 waves x 64)
#define KC 32          // k per staged chunk (= one MFMA K)
#define NCHUNK 8       // DIM/KC
#define NCH 16         // anchor chunks (50000/16 = 3125)
#define CHUNK 3125
#define NTILES 13      // ceil(3125/256)
#define CAP 64         // candidate slots per row per round

typedef __attribute__((ext_vector_type(8))) short bf16x8;   // 8 bf16 in 4 VGPRs
typedef __attribute__((ext_vector_type(4))) float f32x4;

// LDS byte offsets inside sMem (40 KB)
#define OFF_BHI 0          // anchors hi: slot = kq*256 + a, 16B/slot -> 16 KB
#define OFF_BLO 16384      // anchors lo: 16 KB
#define OFF_AHI 32768      // feats hi:   slot = kq*64 + r -> 4 KB
#define OFF_ALO 36864      // feats lo:   4 KB
#define SMEM_BYTES 40960

__device__ __forceinline__ void gl_lds16(const void* g, void* l) {
    // async global->LDS, 16B/lane; LDS dest = uniform base + lane*16
    __builtin_amdgcn_global_load_lds(
        (const __attribute__((address_space(1))) unsigned int*)g,
        (__attribute__((address_space(3))) unsigned int*)l, 16, 0, 0);
}

__device__ __forceinline__ bool lex_better(float v1, int i1, float v2, int i2) {
    return (v1 > v2) || (v1 == v2 && i1 < i2);   // jax top_k order, strict total
}

__device__ __forceinline__ unsigned short f2bf(float x) {
    unsigned u = __float_as_uint(x);
    u += 0x7FFFu + ((u >> 16) & 1u);             // RNE
    return (unsigned short)(u >> 16);
}

// K0: split fp32 -> bf16 hi + bf16 lo (x ~= hi + lo to ~2^-17 rel)
__global__ void split_bf16(const float* __restrict__ x,
                           unsigned short* __restrict__ hi,
                           unsigned short* __restrict__ lo, int n4)
{
    int i = blockIdx.x * blockDim.x + threadIdx.x;
    const int stride = gridDim.x * blockDim.x;
    const float4* X4 = (const float4*)x;
    for (; i < n4; i += stride) {
        float4 v = X4[i];
        ushort4 h, l;
        float f;
        h.x = f2bf(v.x); f = v.x - __uint_as_float((unsigned)h.x << 16); l.x = f2bf(f);
        h.y = f2bf(v.y); f = v.y - __uint_as_float((unsigned)h.y << 16); l.y = f2bf(f);
        h.z = f2bf(v.z); f = v.z - __uint_as_float((unsigned)h.z << 16); l.z = f2bf(f);
        h.w = f2bf(v.w); f = v.w - __uint_as_float((unsigned)h.w << 16); l.w = f2bf(f);
        ((ushort4*)hi)[i] = h;
        ((ushort4*)lo)[i] = l;
    }
}

// K1: 3-pass bf16 MFMA GEMM (exact to ~1e-4) + exact per-(row,chunk) top-50.
// 64x256 block tile, 4 waves; wave w owns anchors [64w,64w+64): 4x4 subtiles 16x16.
// Selection: atomic candidate lists + wave-cooperative BINARY-SEARCH rank-merge.
__global__ __launch_bounds__(256, 2)
void knn_mfma_topk(const unsigned short* __restrict__ fhi,
                   const unsigned short* __restrict__ flo,
                   const unsigned short* __restrict__ ahi,
                   const unsigned short* __restrict__ alo,
                   float* __restrict__ cv, int* __restrict__ ci)
{
    __shared__ __align__(16) unsigned char sMem[SMEM_BYTES];
    __shared__ uint2 s_top[BT][TOPK];                // SORTED top-50 (v desc, idx asc), packed
    __shared__ float s_rowmin[BT];                   // current 50th-best (-inf while filling)
    __shared__ int   s_cnt2[BT];                     // stored count (<= 50)
    __shared__ int   s_pcnt[2][BT];
    __shared__ int   s_more[2];
    __shared__ int   s_tmprs[4][CAP];                // per-wave scratch: cand insert-pos by cand-rank

    uint2* cand = (uint2*)sMem;                      // 32 KB alias of B buffers (dead in selection)

    const int tid  = threadIdx.x;
    const int w    = tid >> 6;        // wave 0..3
    const int lane = tid & 63;
    const int quad = lane >> 4;
    const int lx   = lane & 15;
    const int rbase = blockIdx.x * BT;
    const int cbase = blockIdx.y * CHUNK;

    if (tid < BT) { s_rowmin[tid] = -INFINITY; s_cnt2[tid] = 0; }

    const int tB = w * 4;                            // B staging instr ids for this wave
    const int frow = rbase + lane;                   // A staging row

    for (int tile = 0; tile < NTILES; ++tile) {
        const int abase = cbase + tile * AT;
        const int valid = min(AT, cbase + CHUNK - abase);   // tail tile: 53

        // clamped anchor rows for this wave's 4 B staging instrs
        int garow[4];
        #pragma unroll
        for (int i = 0; i < 4; ++i) {
            int t = tB + i;
            int a = ((t & 3) << 6) + lane;           // slot = t*64+lane -> a = (t&3)*64+lane
            int g = abase + a; if (g > N_ANCH - 1) g = N_ANCH - 1;
            garow[i] = g;
        }

        f32x4 acc[4][4];
        const f32x4 z = {0.f, 0.f, 0.f, 0.f};
        #pragma unroll
        for (int tm = 0; tm < 4; ++tm)
            #pragma unroll
            for (int tn = 0; tn < 4; ++tn) acc[tm][tn] = z;

        for (int c = 0; c < NCHUNK; ++c) {
            __syncthreads();        // prev chunk frag reads / prev selection done
            const int kb = c * KC;
            // stage anchors: slot = kq*256 + a  (kq = t>>2), 16B/slot
            #pragma unroll
            for (int i = 0; i < 4; ++i) {
                int t = tB + i;
                size_t goff = (size_t)garow[i] * DIM + kb + ((t >> 2) << 3);
                gl_lds16(ahi + goff, sMem + OFF_BHI + t * 1024);
                gl_lds16(alo + goff, sMem + OFF_BLO + t * 1024);
            }
            // stage feats: slot = kq*64 + r (kq = w)
            {
                size_t goff = (size_t)frow * DIM + kb + (w << 3);
                gl_lds16(fhi + goff, sMem + OFF_AHI + w * 1024);
                gl_lds16(flo + goff, sMem + OFF_ALO + w * 1024);
            }
            __syncthreads();        // vmcnt drained by compiler before barrier

            // fragments: lane holds [idx = lane&15][k = quad*8 + j]
            bf16x8 bh[4], bl[4], ah[4], al[4];
            #pragma unroll
            for (int tn = 0; tn < 4; ++tn) {
                int a = (w << 6) + (tn << 4) + lx;
                int off = (quad << 12) + (a << 4);      // (kq*256 + a)*16
                bh[tn] = *(const bf16x8*)(sMem + OFF_BHI + off);
                bl[tn] = *(const bf16x8*)(sMem + OFF_BLO + off);
            }
            #pragma unroll
            for (int tm = 0; tm < 4; ++tm) {
                int r = (tm << 4) + lx;
                int off = (quad << 10) + (r << 4);      // (kq*64 + r)*16
                ah[tm] = *(const bf16x8*)(sMem + OFF_AHI + off);
                al[tm] = *(const bf16x8*)(sMem + OFF_ALO + off);
            }
            // 3-pass: A*B ~= Ah*Bh + Al*Bh + Ah*Bl  (drop Al*Bl ~ 2^-18)
            #pragma unroll
            for (int tm = 0; tm < 4; ++tm)
                #pragma unroll
                for (int tn = 0; tn < 4; ++tn) {
                    acc[tm][tn] = __builtin_amdgcn_mfma_f32_16x16x32_bf16(ah[tm], bh[tn], acc[tm][tn], 0, 0, 0);
                    acc[tm][tn] = __builtin_amdgcn_mfma_f32_16x16x32_bf16(al[tm], bh[tn], acc[tm][tn], 0, 0, 0);
                    acc[tm][tn] = __builtin_amdgcn_mfma_f32_16x16x32_bf16(ah[tm], bl[tn], acc[tm][tn], 0, 0, 0);
                }
        }

        // ---- candidate selection (cand aliases B buffers) ----
        // C/D layout: row m = quad*4 + reg (+16*tm), col n = lx (+16*tn, +64*w)
        if (tid < BT) s_pcnt[0][tid] = 0;
        if (tid == 0) s_more[0] = 0;
        __syncthreads();

        unsigned rmask[4];
        #pragma unroll
        for (int tm = 0; tm < 4; ++tm) rmask[tm] = 0xFFFFu;

        int p = 0;
        for (int round = 0; round < 8; ++round) {
            // push phase: atomic slot grab into dense per-row list
            #pragma unroll
            for (int tm = 0; tm < 4; ++tm) {
                unsigned m = rmask[tm];
                if (!m) continue;
                float rmv[4];
                #pragma unroll
                for (int reg = 0; reg < 4; ++reg)
                    rmv[reg] = s_rowmin[(tm << 4) + (quad << 2) + reg];
                #pragma unroll
                for (int tn = 0; tn < 4; ++tn) {
                    #pragma unroll
                    for (int reg = 0; reg < 4; ++reg) {
                        const unsigned bit = 1u << (tn * 4 + reg);
                        if (m & bit) {
                            const int   r    = (tm << 4) + (quad << 2) + reg;
                            const int   aoff = (w << 6) + (tn << 4) + lx;
                            const float v    = acc[tm][tn][reg];
                            if (aoff < valid && v >= rmv[reg]) {
                                int slot = atomicAdd(&s_pcnt[p][r], 1);
                                if (slot < CAP) {
                                    cand[r * CAP + slot] =
                                        make_uint2(__float_as_uint(v), (unsigned)(abase + aoff));
                                    m &= ~bit;
                                } else {
                                    s_more[p] = 1;      // deferred; retry
                                }
                            } else {
                                m &= ~bit;              // rejected (rowmin only rises) or OOB
                            }
                        }
                    }
                }
                rmask[tm] = m;
            }
            if (tid < BT) s_pcnt[p ^ 1][tid] = 0;
            if (tid == 0) s_more[p ^ 1] = 0;
            __syncthreads();
            const int more = s_more[p];                  // uniform between barriers

            // wave-cooperative binary-search rank-merge: wave w handles rows 16w..16w+15
            for (int rr = 0; rr < 16; ++rr) {
                const int r = (w << 4) + rr;
                int cnt = s_pcnt[p][r]; if (cnt > CAP) cnt = CAP;
                if (cnt == 0) continue;                  // wave-uniform
                const int k0   = s_cnt2[r];
                const int pool = k0 + cnt;

                // my candidate (lane < cnt) and my stored element (lane < k0)
                uint2 myc = cand[r * CAP + lane];        // stale beyond cnt: masked below
                float vc = __uint_as_float(myc.x); int icd = (int)myc.y;
                uint2 mys = s_top[r][lane < TOPK ? lane : TOPK - 1];
                float vs = __uint_as_float(mys.x); int isd = (int)mys.y;

                // rc: rank among candidates (broadcast scan, cnt iters)
                int rc = 0;
                for (int q = 0; q < cnt; ++q) {
                    uint2 cq = cand[r * CAP + q];
                    float vq = __uint_as_float(cq.x); int iq = (int)cq.y;
                    rc += lex_better(vq, iq, vc, icd);
                }
                // rs: #stored better than my candidate (binary search, sorted desc)
                int lo = 0, hi = k0;
                #pragma unroll
                for (int it = 0; it < 7; ++it) {
                    int mid = (lo + hi) >> 1;
                    uint2 t = s_top[r][mid < TOPK ? mid : TOPK - 1];
                    bool b  = lex_better(__uint_as_float(t.x), (int)t.y, vc, icd);
                    bool go = lo < hi;
                    lo = (go && b)  ? mid + 1 : lo;
                    hi = (go && !b) ? mid : hi;
                }
                const int rs = lo;
                const int fc = rc + rs;                  // candidate final rank

                // scatter insert-pos by cand-rank (monotone => sorted non-decreasing)
                if (lane < cnt) s_tmprs[w][rc] = rs;
                asm volatile("s_waitcnt lgkmcnt(0)" ::: "memory");
                // #cands better than stored[lane] = first idx with tmprs > lane
                int lo2 = 0, hi2 = cnt;
                #pragma unroll
                for (int it = 0; it < 7; ++it) {
                    int mid = (lo2 + hi2) >> 1;
                    int rv  = s_tmprs[w][mid < CAP ? mid : CAP - 1];
                    bool b  = (rv <= lane);
                    bool go = lo2 < hi2;
                    lo2 = (go && b)  ? mid + 1 : lo2;
                    hi2 = (go && !b) ? mid : hi2;
                }
                const int fs = lane + lo2;               // stored final rank

                // all s_top reads done; writes now (wave program order). Ranks unique.
                if (lane < cnt && fc < TOPK) s_top[r][fc] = myc;
                if (lane < k0  && fs < TOPK) s_top[r][fs] = mys;
                if (lane < cnt && fc == TOPK - 1) s_rowmin[r] = vc;
                if (lane < k0  && fs == TOPK - 1) s_rowmin[r] = vs;
                if (lane == 0) s_cnt2[r] = (pool < TOPK) ? pool : TOPK;
            }
            __syncthreads();
            if (!more) break;
            p ^= 1;
        }
    }
    __syncthreads();
    // write per-(row,chunk) top-50 (sorted; K2 treats as unordered set)
    for (int e = tid; e < BT * TOPK; e += 256) {
        int row = e / TOPK, j = e % TOPK;
        uint2 cc = s_top[row][j];
        size_t g = ((size_t)(rbase + row) * NCH + blockIdx.y) * TOPK + j;
        cv[g] = __uint_as_float(cc.x);
        ci[g] = (int)cc.y;
    }
}

// K2: exact merge of 16 runs of 50 -> top-50, then loss / mean_sim.
__global__ __launch_bounds__(256)
void knn_merge(const float* __restrict__ cv, const int* __restrict__ ci,
               const int* __restrict__ labels, const int* __restrict__ anchor_label,
               float* __restrict__ out)
{
    const int M = NCH * TOPK;   // 800
    __shared__ float s_val[NCH*TOPK];
    __shared__ int   s_idx[NCH*TOPK];
    __shared__ float s_sv[NCH*TOPK];
    __shared__ int   s_si[NCH*TOPK];
    __shared__ float s_runmin[NCH];
    __shared__ float s_T;
    __shared__ int   s_ns;
    __shared__ float s_sum;
    __shared__ int   s_cnt;

    const int row = blockIdx.x;
    const int tid = threadIdx.x;

    if (tid == 0) { s_ns = 0; s_sum = 0.f; s_cnt = 0; }
    for (int e = tid; e < M; e += 256) {
        s_val[e] = cv[(size_t)row*M + e];
        s_idx[e] = ci[(size_t)row*M + e];
    }
    __syncthreads();
    if (tid < NCH) {
        float m = INFINITY;
        for (int q = 0; q < TOPK; ++q) m = fminf(m, s_val[tid*TOPK + q]);
        s_runmin[tid] = m;
    }
    __syncthreads();
    if (tid == 0) {
        float t = -INFINITY;
        for (int c = 0; c < NCH; ++c) t = fmaxf(t, s_runmin[c]);
        s_T = t;   // lower bound on global 50th
    }
    __syncthreads();
    const float T = s_T;
    for (int e = tid; e < M; e += 256) {
        float v = s_val[e];
        if (v >= T) {
            int p = atomicAdd(&s_ns, 1);
            s_sv[p] = v; s_si[p] = s_idx[e];
        }
    }
    __syncthreads();
    const int ns = s_ns;             // >= 50 guaranteed
    const int mylab = labels[row];
    for (int s = tid; s < ns; s += 256) {
        float v = s_sv[s]; int id = s_si[s];
        int r = 0;
        for (int q = 0; q < ns; ++q) {
            float vq = s_sv[q];
            r += (vq > v) || (vq == v && s_si[q] < id);   // smaller index wins ties
        }
        if (r < TOPK) {
            atomicAdd(&s_sum, v);
            if (anchor_label[id] == mylab) atomicAdd(&s_cnt, 1);
        }
    }
    __syncthreads();
    if (tid == 0) {
        float mlp = (float)s_cnt / (float)TOPK;
        out[row]          = -mlp;                 // loss
        out[B_ROWS + row] = s_sum / (float)TOPK;  // mean_sim
    }
}

extern "C" void kernel_launch(void* const* d_in, const int* in_sizes, int n_in,
                              void* d_out, int out_size, void* d_ws, size_t ws_size,
                              hipStream_t stream)
{
    const float* feat         = (const float*)d_in[0];
    const float* anc          = (const float*)d_in[1];
    const int*   labels       = (const int*)d_in[2];
    // d_in[3] = t_labels (unused)
    const int*   anchor_label = (const int*)d_in[4];
    float* out = (float*)d_out;

    char* ws = (char*)d_ws;
    size_t off = 0;
    float* cv = (float*)(ws + off);          off += (size_t)B_ROWS * NCH * TOPK * 4;   // 6.55 MB
    int*   ci = (int*)(ws + off);            off += (size_t)B_ROWS * NCH * TOPK * 4;   // 6.55 MB
    unsigned short* fhi = (unsigned short*)(ws + off); off += (size_t)B_ROWS * DIM * 2; // 1.05 MB
    unsigned short* flo = (unsigned short*)(ws + off); off += (size_t)B_ROWS * DIM * 2;
    unsigned short* ahi = (unsigned short*)(ws + off); off += (size_t)N_ANCH * DIM * 2; // 25.6 MB
    unsigned short* alo = (unsigned short*)(ws + off);                                  // 25.6 MB

    hipLaunchKernelGGL(split_bf16, dim3(256), dim3(256), 0, stream,
                       feat, fhi, flo, B_ROWS * DIM / 4);
    hipLaunchKernelGGL(split_bf16, dim3(4096), dim3(256), 0, stream,
                       anc, ahi, alo, N_ANCH * DIM / 4);
    hipLaunchKernelGGL(knn_mfma_topk, dim3(B_ROWS / BT, NCH), dim3(256), 0, stream,
                       fhi, flo, ahi, alo, cv, ci);
    hipLaunchKernelGGL(knn_merge, dim3(B_ROWS), dim3(256), 0, stream,
                       cv, ci, labels, anchor_label, out);
}

// Round 8
// 1540.129 us; speedup vs baseline: 9.7981x; 1.0175x over previous
//
#include <hip/hip_runtime.h>
#include <math.h>

// Problem constants (match setup_inputs)
#define B_ROWS 2048
#define N_ANCH 50000
#define DIM    256
#define TOPK   50

// K1 tiling
#define BT 64          // feature rows per block
#define AT 256         // anchors per tile (4 waves x 64)
#define KC 32          // k per staged chunk (= one MFMA K)
#define NCHUNK 8       // DIM/KC
#define NCH 16         // anchor chunks (50000/16 = 3125)
#define CHUNK 3125
#define NTILES 13      // ceil(3125/256)
#define CAP 64         // candidate slots per row per round (sample kernel)
#define CAPG 1024      // global append capacity per row (E~560, ~6 sigma margin)

typedef __attribute__((ext_vector_type(8))) short bf16x8;   // 8 bf16 in 4 VGPRs
typedef __attribute__((ext_vector_type(4))) float f32x4;

// LDS byte offsets inside sMem (40 KB)
#define OFF_BHI 0          // anchors hi: slot = kq*256 + a, 16B/slot -> 16 KB
#define OFF_BLO 16384      // anchors lo: 16 KB
#define OFF_AHI 32768      // feats hi:   slot = kq*64 + r -> 4 KB
#define OFF_ALO 36864      // feats lo:   4 KB
#define SMEM_BYTES 40960

__device__ __forceinline__ void gl_lds16(const void* g, void* l) {
    // async global->LDS, 16B/lane; LDS dest = uniform base + lane*16
    __builtin_amdgcn_global_load_lds(
        (const __attribute__((address_space(1))) unsigned int*)g,
        (__attribute__((address_space(3))) unsigned int*)l, 16, 0, 0);
}

__device__ __forceinline__ bool lex_better(float v1, int i1, float v2, int i2) {
    return (v1 > v2) || (v1 == v2 && i1 < i2);   // jax top_k order, strict total
}

__device__ __forceinline__ unsigned short f2bf(float x) {
    unsigned u = __float_as_uint(x);
    u += 0x7FFFu + ((u >> 16) & 1u);             // RNE
    return (unsigned short)(u >> 16);
}

// K0: split fp32 -> bf16 hi + bf16 lo (x ~= hi + lo to ~2^-17 rel)
__global__ void split_bf16(const float* __restrict__ x,
                           unsigned short* __restrict__ hi,
                           unsigned short* __restrict__ lo, int n4)
{
    int i = blockIdx.x * blockDim.x + threadIdx.x;
    const int stride = gridDim.x * blockDim.x;
    const float4* X4 = (const float4*)x;
    for (; i < n4; i += stride) {
        float4 v = X4[i];
        ushort4 h, l;
        float f;
        h.x = f2bf(v.x); f = v.x - __uint_as_float((unsigned)h.x << 16); l.x = f2bf(f);
        h.y = f2bf(v.y); f = v.y - __uint_as_float((unsigned)h.y << 16); l.y = f2bf(f);
        h.z = f2bf(v.z); f = v.z - __uint_as_float((unsigned)h.z << 16); l.z = f2bf(f);
        h.w = f2bf(v.w); f = v.w - __uint_as_float((unsigned)h.w << 16); l.w = f2bf(f);
        ((ushort4*)hi)[i] = h;
        ((ushort4*)lo)[i] = l;
    }
}

__global__ void zero_cnt(int* __restrict__ cnt)
{
    int i = blockIdx.x * blockDim.x + threadIdx.x;
    if (i < B_ROWS) cnt[i] = 0;
}

// SAMPLE kernel: 3-pass bf16 MFMA GEMM + exact per-(row,chunk) top-50 over the
// first `ntiles` tiles of each chunk. (Round-7-verified machinery, ntiles now a param.)
__global__ __launch_bounds__(256, 2)
void knn_mfma_topk(const unsigned short* __restrict__ fhi,
                   const unsigned short* __restrict__ flo,
                   const unsigned short* __restrict__ ahi,
                   const unsigned short* __restrict__ alo,
                   float* __restrict__ cv, int* __restrict__ ci, int ntiles)
{
    __shared__ __align__(16) unsigned char sMem[SMEM_BYTES];
    __shared__ uint2 s_top[BT][TOPK];                // SORTED top-50 (v desc, idx asc)
    __shared__ float s_rowmin[BT];
    __shared__ int   s_cnt2[BT];
    __shared__ int   s_pcnt[2][BT];
    __shared__ int   s_more[2];
    __shared__ int   s_tmprs[4][CAP];

    uint2* cand = (uint2*)sMem;                      // aliases B buffers (dead in selection)

    const int tid  = threadIdx.x;
    const int w    = tid >> 6;
    const int lane = tid & 63;
    const int quad = lane >> 4;
    const int lx   = lane & 15;
    const int rbase = blockIdx.x * BT;
    const int cbase = blockIdx.y * CHUNK;

    if (tid < BT) { s_rowmin[tid] = -INFINITY; s_cnt2[tid] = 0; }

    const int tB = w * 4;
    const int frow = rbase + lane;

    for (int tile = 0; tile < ntiles; ++tile) {
        const int abase = cbase + tile * AT;
        const int valid = min(AT, cbase + CHUNK - abase);

        int garow[4];
        #pragma unroll
        for (int i = 0; i < 4; ++i) {
            int t = tB + i;
            int a = ((t & 3) << 6) + lane;
            int g = abase + a; if (g > N_ANCH - 1) g = N_ANCH - 1;
            garow[i] = g;
        }

        f32x4 acc[4][4];
        const f32x4 z = {0.f, 0.f, 0.f, 0.f};
        #pragma unroll
        for (int tm = 0; tm < 4; ++tm)
            #pragma unroll
            for (int tn = 0; tn < 4; ++tn) acc[tm][tn] = z;

        for (int c = 0; c < NCHUNK; ++c) {
            __syncthreads();
            const int kb = c * KC;
            #pragma unroll
            for (int i = 0; i < 4; ++i) {
                int t = tB + i;
                size_t goff = (size_t)garow[i] * DIM + kb + ((t >> 2) << 3);
                gl_lds16(ahi + goff, sMem + OFF_BHI + t * 1024);
                gl_lds16(alo + goff, sMem + OFF_BLO + t * 1024);
            }
            {
                size_t goff = (size_t)frow * DIM + kb + (w << 3);
                gl_lds16(fhi + goff, sMem + OFF_AHI + w * 1024);
                gl_lds16(flo + goff, sMem + OFF_ALO + w * 1024);
            }
            __syncthreads();

            bf16x8 bh[4], bl[4], ah[4], al[4];
            #pragma unroll
            for (int tn = 0; tn < 4; ++tn) {
                int a = (w << 6) + (tn << 4) + lx;
                int off = (quad << 12) + (a << 4);
                bh[tn] = *(const bf16x8*)(sMem + OFF_BHI + off);
                bl[tn] = *(const bf16x8*)(sMem + OFF_BLO + off);
            }
            #pragma unroll
            for (int tm = 0; tm < 4; ++tm) {
                int r = (tm << 4) + lx;
                int off = (quad << 10) + (r << 4);
                ah[tm] = *(const bf16x8*)(sMem + OFF_AHI + off);
                al[tm] = *(const bf16x8*)(sMem + OFF_ALO + off);
            }
            #pragma unroll
            for (int tm = 0; tm < 4; ++tm)
                #pragma unroll
                for (int tn = 0; tn < 4; ++tn) {
                    acc[tm][tn] = __builtin_amdgcn_mfma_f32_16x16x32_bf16(ah[tm], bh[tn], acc[tm][tn], 0, 0, 0);
                    acc[tm][tn] = __builtin_amdgcn_mfma_f32_16x16x32_bf16(al[tm], bh[tn], acc[tm][tn], 0, 0, 0);
                    acc[tm][tn] = __builtin_amdgcn_mfma_f32_16x16x32_bf16(ah[tm], bl[tn], acc[tm][tn], 0, 0, 0);
                }
        }

        // ---- candidate selection ----
        if (tid < BT) s_pcnt[0][tid] = 0;
        if (tid == 0) s_more[0] = 0;
        __syncthreads();

        unsigned rmask[4];
        #pragma unroll
        for (int tm = 0; tm < 4; ++tm) rmask[tm] = 0xFFFFu;

        int p = 0;
        for (int round = 0; round < 8; ++round) {
            #pragma unroll
            for (int tm = 0; tm < 4; ++tm) {
                unsigned m = rmask[tm];
                if (!m) continue;
                float rmv[4];
                #pragma unroll
                for (int reg = 0; reg < 4; ++reg)
                    rmv[reg] = s_rowmin[(tm << 4) + (quad << 2) + reg];
                #pragma unroll
                for (int tn = 0; tn < 4; ++tn) {
                    #pragma unroll
                    for (int reg = 0; reg < 4; ++reg) {
                        const unsigned bit = 1u << (tn * 4 + reg);
                        if (m & bit) {
                            const int   r    = (tm << 4) + (quad << 2) + reg;
                            const int   aoff = (w << 6) + (tn << 4) + lx;
                            const float v    = acc[tm][tn][reg];
                            if (aoff < valid && v >= rmv[reg]) {
                                int slot = atomicAdd(&s_pcnt[p][r], 1);
                                if (slot < CAP) {
                                    cand[r * CAP + slot] =
                                        make_uint2(__float_as_uint(v), (unsigned)(abase + aoff));
                                    m &= ~bit;
                                } else {
                                    s_more[p] = 1;
                                }
                            } else {
                                m &= ~bit;
                            }
                        }
                    }
                }
                rmask[tm] = m;
            }
            if (tid < BT) s_pcnt[p ^ 1][tid] = 0;
            if (tid == 0) s_more[p ^ 1] = 0;
            __syncthreads();
            const int more = s_more[p];

            for (int rr = 0; rr < 16; ++rr) {
                const int r = (w << 4) + rr;
                int cnt = s_pcnt[p][r]; if (cnt > CAP) cnt = CAP;
                if (cnt == 0) continue;
                const int k0   = s_cnt2[r];
                const int pool = k0 + cnt;

                uint2 myc = cand[r * CAP + lane];
                float vc = __uint_as_float(myc.x); int icd = (int)myc.y;
                uint2 mys = s_top[r][lane < TOPK ? lane : TOPK - 1];
                float vs = __uint_as_float(mys.x); int isd = (int)mys.y;

                int rc = 0;
                for (int q = 0; q < cnt; ++q) {
                    uint2 cq = cand[r * CAP + q];
                    float vq = __uint_as_float(cq.x); int iq = (int)cq.y;
                    rc += lex_better(vq, iq, vc, icd);
                }
                int lo = 0, hi = k0;
                #pragma unroll
                for (int it = 0; it < 7; ++it) {
                    int mid = (lo + hi) >> 1;
                    uint2 t = s_top[r][mid < TOPK ? mid : TOPK - 1];
                    bool b  = lex_better(__uint_as_float(t.x), (int)t.y, vc, icd);
                    bool go = lo < hi;
                    lo = (go && b)  ? mid + 1 : lo;
                    hi = (go && !b) ? mid : hi;
                }
                const int rs = lo;
                const int fc = rc + rs;

                if (lane < cnt) s_tmprs[w][rc] = rs;
                asm volatile("s_waitcnt lgkmcnt(0)" ::: "memory");
                int lo2 = 0, hi2 = cnt;
                #pragma unroll
                for (int it = 0; it < 7; ++it) {
                    int mid = (lo2 + hi2) >> 1;
                    int rv  = s_tmprs[w][mid < CAP ? mid : CAP - 1];
                    bool b  = (rv <= lane);
                    bool go = lo2 < hi2;
                    lo2 = (go && b)  ? mid + 1 : lo2;
                    hi2 = (go && !b) ? mid : hi2;
                }
                const int fs = lane + lo2;

                if (lane < cnt && fc < TOPK) s_top[r][fc] = myc;
                if (lane < k0  && fs < TOPK) s_top[r][fs] = mys;
                if (lane < cnt && fc == TOPK - 1) s_rowmin[r] = vc;
                if (lane < k0  && fs == TOPK - 1) s_rowmin[r] = vs;
                if (lane == 0) s_cnt2[r] = (pool < TOPK) ? pool : TOPK;
            }
            __syncthreads();
            if (!more) break;
            p ^= 1;
        }
    }
    __syncthreads();
    for (int e = tid; e < BT * TOPK; e += 256) {
        int row = e / TOPK, j = e % TOPK;
        uint2 cc = s_top[row][j];
        size_t g = ((size_t)(rbase + row) * NCH + blockIdx.y) * TOPK + j;
        cv[g] = __uint_as_float(cc.x);
        ci[g] = (int)cc.y;
    }
}

// KT: T[row] = 50th-largest VALUE of the row's 800 sample-top values
//    (= exact 50th of the 4096-anchor sample; structurally <= true 50th of 50000).
__global__ __launch_bounds__(256)
void thresh50(const float* __restrict__ cv, float* __restrict__ Tarr)
{
    __shared__ float sv[NCH * TOPK];
    const int row = blockIdx.x;
    const int tid = threadIdx.x;
    for (int e = tid; e < NCH * TOPK; e += 256) sv[e] = cv[(size_t)row * NCH * TOPK + e];
    __syncthreads();
    for (int e = tid; e < NCH * TOPK; e += 256) {
        float v = sv[e];
        int c1 = 0, ce = 0;
        for (int q = 0; q < NCH * TOPK; ++q) {
            float u = sv[q];
            c1 += (u > v); ce += (u == v);
        }
        if (c1 <= TOPK - 1 && c1 + ce >= TOPK) Tarr[row] = v;   // benign dup-write on ties
    }
}

// APPEND kernel: pure 3-pass MFMA GEMM over tiles 1..12 of each chunk;
// per element just threshold-test and append to the row's global list.
__global__ __launch_bounds__(256, 3)
void knn_mfma_append(const unsigned short* __restrict__ fhi,
                     const unsigned short* __restrict__ flo,
                     const unsigned short* __restrict__ ahi,
                     const unsigned short* __restrict__ alo,
                     const float* __restrict__ Tarr,
                     uint2* __restrict__ cand, int* __restrict__ cnt)
{
    __shared__ __align__(16) unsigned char sMem[SMEM_BYTES];
    __shared__ float s_T[BT];

    const int tid  = threadIdx.x;
    const int w    = tid >> 6;
    const int lane = tid & 63;
    const int quad = lane >> 4;
    const int lx   = lane & 15;
    const int rbase = blockIdx.x * BT;
    const int cbase = blockIdx.y * CHUNK;

    if (tid < BT) s_T[tid] = Tarr[rbase + tid];
    __syncthreads();
    float thr[4][4];
    #pragma unroll
    for (int tm = 0; tm < 4; ++tm)
        #pragma unroll
        for (int reg = 0; reg < 4; ++reg)
            thr[tm][reg] = s_T[(tm << 4) + (quad << 2) + reg];

    const int tB = w * 4;
    const int frow = rbase + lane;

    for (int tile = 1; tile < NTILES; ++tile) {
        const int abase = cbase + tile * AT;
        const int valid = min(AT, cbase + CHUNK - abase);   // tail tile: 53

        int garow[4];
        #pragma unroll
        for (int i = 0; i < 4; ++i) {
            int t = tB + i;
            int a = ((t & 3) << 6) + lane;
            int g = abase + a; if (g > N_ANCH - 1) g = N_ANCH - 1;
            garow[i] = g;
        }

        f32x4 acc[4][4];
        const f32x4 z = {0.f, 0.f, 0.f, 0.f};
        #pragma unroll
        for (int tm = 0; tm < 4; ++tm)
            #pragma unroll
            for (int tn = 0; tn < 4; ++tn) acc[tm][tn] = z;

        for (int c = 0; c < NCHUNK; ++c) {
            __syncthreads();        // prev chunk frag reads done (append touches no LDS)
            const int kb = c * KC;
            #pragma unroll
            for (int i = 0; i < 4; ++i) {
                int t = tB + i;
                size_t goff = (size_t)garow[i] * DIM + kb + ((t >> 2) << 3);
                gl_lds16(ahi + goff, sMem + OFF_BHI + t * 1024);
                gl_lds16(alo + goff, sMem + OFF_BLO + t * 1024);
            }
            {
                size_t goff = (size_t)frow * DIM + kb + (w << 3);
                gl_lds16(fhi + goff, sMem + OFF_AHI + w * 1024);
                gl_lds16(flo + goff, sMem + OFF_ALO + w * 1024);
            }
            __syncthreads();

            bf16x8 bh[4], bl[4], ah[4], al[4];
            #pragma unroll
            for (int tn = 0; tn < 4; ++tn) {
                int a = (w << 6) + (tn << 4) + lx;
                int off = (quad << 12) + (a << 4);
                bh[tn] = *(const bf16x8*)(sMem + OFF_BHI + off);
                bl[tn] = *(const bf16x8*)(sMem + OFF_BLO + off);
            }
            #pragma unroll
            for (int tm = 0; tm < 4; ++tm) {
                int r = (tm << 4) + lx;
                int off = (quad << 10) + (r << 4);
                ah[tm] = *(const bf16x8*)(sMem + OFF_AHI + off);
                al[tm] = *(const bf16x8*)(sMem + OFF_ALO + off);
            }
            #pragma unroll
            for (int tm = 0; tm < 4; ++tm)
                #pragma unroll
                for (int tn = 0; tn < 4; ++tn) {
                    acc[tm][tn] = __builtin_amdgcn_mfma_f32_16x16x32_bf16(ah[tm], bh[tn], acc[tm][tn], 0, 0, 0);
                    acc[tm][tn] = __builtin_amdgcn_mfma_f32_16x16x32_bf16(al[tm], bh[tn], acc[tm][tn], 0, 0, 0);
                    acc[tm][tn] = __builtin_amdgcn_mfma_f32_16x16x32_bf16(ah[tm], bl[tn], acc[tm][tn], 0, 0, 0);
                }
        }

        // threshold-filtered global append (C/D: row = 16tm+4quad+reg, col = 64w+16tn+lx)
        #pragma unroll
        for (int tm = 0; tm < 4; ++tm)
            #pragma unroll
            for (int tn = 0; tn < 4; ++tn)
                #pragma unroll
                for (int reg = 0; reg < 4; ++reg) {
                    const float v    = acc[tm][tn][reg];
                    const int   aoff = (w << 6) + (tn << 4) + lx;
                    if (aoff < valid && v >= thr[tm][reg]) {
                        const int row = rbase + (tm << 4) + (quad << 2) + reg;
                        int slot = atomicAdd(&cnt[row], 1);
                        if (slot < CAPG)
                            cand[(size_t)row * CAPG + slot] =
                                make_uint2(__float_as_uint(v), (unsigned)(abase + aoff));
                        // slot >= CAPG: ~6-sigma event for this fixed input; clamped
                    }
                }
    }
}

// FINAL: pool = (cv entries >= T) U (appended) -> exact lex top-50 -> outputs.
__global__ __launch_bounds__(256)
void knn_final(const float* __restrict__ cv, const int* __restrict__ ci,
               const uint2* __restrict__ cand, const int* __restrict__ cnt,
               const float* __restrict__ Tarr,
               const int* __restrict__ labels, const int* __restrict__ anchor_label,
               float* __restrict__ out)
{
    const int M = NCH * TOPK;   // 800
    __shared__ float pv[NCH*TOPK + CAPG];
    __shared__ int   pi[NCH*TOPK + CAPG];
    __shared__ int   s_ns;
    __shared__ float s_sum;
    __shared__ int   s_cm;

    const int row = blockIdx.x;
    const int tid = threadIdx.x;
    if (tid == 0) { s_ns = 0; s_sum = 0.f; s_cm = 0; }
    __syncthreads();

    const float T = Tarr[row];
    for (int e = tid; e < M; e += 256) {
        float v = cv[(size_t)row * M + e];
        if (v >= T) {
            int p = atomicAdd(&s_ns, 1);
            pv[p] = v; pi[p] = ci[(size_t)row * M + e];
        }
    }
    int cr = cnt[row]; if (cr > CAPG) cr = CAPG;
    for (int e = tid; e < cr; e += 256) {
        uint2 c = cand[(size_t)row * CAPG + e];
        int p = atomicAdd(&s_ns, 1);
        pv[p] = __uint_as_float(c.x); pi[p] = (int)c.y;
    }
    __syncthreads();
    const int ns = s_ns;             // >= 50 guaranteed (>=50 cv entries >= T)
    const int mylab = labels[row];
    for (int s = tid; s < ns; s += 256) {
        float v = pv[s]; int id = pi[s];
        int r = 0;
        for (int q = 0; q < ns; ++q) {
            float vq = pv[q];
            r += (vq > v) || (vq == v && pi[q] < id);   // smaller index wins ties
        }
        if (r < TOPK) {
            atomicAdd(&s_sum, v);
            if (anchor_label[id] == mylab) atomicAdd(&s_cm, 1);
        }
    }
    __syncthreads();
    if (tid == 0) {
        float mlp = (float)s_cm / (float)TOPK;
        out[row]          = -mlp;                 // loss
        out[B_ROWS + row] = s_sum / (float)TOPK;  // mean_sim
    }
}

extern "C" void kernel_launch(void* const* d_in, const int* in_sizes, int n_in,
                              void* d_out, int out_size, void* d_ws, size_t ws_size,
                              hipStream_t stream)
{
    const float* feat         = (const float*)d_in[0];
    const float* anc          = (const float*)d_in[1];
    const int*   labels       = (const int*)d_in[2];
    // d_in[3] = t_labels (unused)
    const int*   anchor_label = (const int*)d_in[4];
    float* out = (float*)d_out;

    char* ws = (char*)d_ws;
    size_t off = 0;
    float* cv = (float*)(ws + off);          off += (size_t)B_ROWS * NCH * TOPK * 4;    // 6.55 MB
    int*   ci = (int*)(ws + off);            off += (size_t)B_ROWS * NCH * TOPK * 4;    // 6.55 MB
    unsigned short* fhi = (unsigned short*)(ws + off); off += (size_t)B_ROWS * DIM * 2; // 1.05 MB
    unsigned short* flo = (unsigned short*)(ws + off); off += (size_t)B_ROWS * DIM * 2;
    unsigned short* ahi = (unsigned short*)(ws + off); off += (size_t)N_ANCH * DIM * 2; // 25.6 MB
    unsigned short* alo = (unsigned short*)(ws + off); off += (size_t)N_ANCH * DIM * 2; // 25.6 MB
    uint2* cand = (uint2*)(ws + off);        off += (size_t)B_ROWS * CAPG * 8;          // 16.8 MB
    int*   cnt  = (int*)(ws + off);          off += (size_t)B_ROWS * 4;
    float* Tarr = (float*)(ws + off);        off += (size_t)B_ROWS * 4;                 // total ~83 MB

    hipLaunchKernelGGL(split_bf16, dim3(256), dim3(256), 0, stream,
                       feat, fhi, flo, B_ROWS * DIM / 4);
    hipLaunchKernelGGL(split_bf16, dim3(4096), dim3(256), 0, stream,
                       anc, ahi, alo, N_ANCH * DIM / 4);
    hipLaunchKernelGGL(zero_cnt, dim3(8), dim3(256), 0, stream, cnt);
    hipLaunchKernelGGL(knn_mfma_topk, dim3(B_ROWS / BT, NCH), dim3(256), 0, stream,
                       fhi, flo, ahi, alo, cv, ci, 1);          // sample: tile 0 only
    hipLaunchKernelGGL(thresh50, dim3(B_ROWS), dim3(256), 0, stream, cv, Tarr);
    hipLaunchKernelGGL(knn_mfma_append, dim3(B_ROWS / BT, NCH), dim3(256), 0, stream,
                       fhi, flo, ahi, alo, Tarr, cand, cnt);    // tiles 1..12
    hipLaunchKernelGGL(knn_final, dim3(B_ROWS), dim3(256), 0, stream,
                       cv, ci, cand, cnt, Tarr, labels, anchor_label, out);
}

// Round 9
// 1075.046 us; speedup vs baseline: 14.0370x; 1.4326x over previous
//
#include <hip/hip_runtime.h>
#include <math.h>

// Problem constants (match setup_inputs)
#define B_ROWS 2048
#define N_ANCH 50000
#define DIM    256
#define TOPK   50

// K1 tiling
#define BT 64          // feature rows per block
#define AT 256         // anchors per tile (4 waves x 64)
#define KC 32          // k per staged chunk (= one MFMA K)
#define NCHUNK 8       // DIM/KC
#define NCH 16         // anchor chunks (50000/16 = 3125)
#define CHUNK 3125
#define NTILES 13      // ceil(3125/256)
#define CAP 64         // candidate slots per row per round (sample kernel)
#define CAPG 1024      // global append capacity per row (E~700 w/ clo<=64)

typedef __attribute__((ext_vector_type(8))) short bf16x8;   // 8 bf16 in 4 VGPRs
typedef __attribute__((ext_vector_type(4))) float f32x4;

// LDS byte offsets inside sMem (40 KB)
#define OFF_BHI 0          // anchors hi: slot = kq*256 + a, 16B/slot -> 16 KB
#define OFF_BLO 16384      // anchors lo: 16 KB
#define OFF_AHI 32768      // feats hi:   slot = kq*64 + r -> 4 KB
#define OFF_ALO 36864      // feats lo:   4 KB
#define SMEM_BYTES 40960

__device__ __forceinline__ void gl_lds16(const void* g, void* l) {
    __builtin_amdgcn_global_load_lds(
        (const __attribute__((address_space(1))) unsigned int*)g,
        (__attribute__((address_space(3))) unsigned int*)l, 16, 0, 0);
}

__device__ __forceinline__ bool lex_better(float v1, int i1, float v2, int i2) {
    return (v1 > v2) || (v1 == v2 && i1 < i2);   // jax top_k order, strict total
}

__device__ __forceinline__ unsigned short f2bf(float x) {
    unsigned u = __float_as_uint(x);
    u += 0x7FFFu + ((u >> 16) & 1u);             // RNE
    return (unsigned short)(u >> 16);
}

// ordered-uint mapping for float (monotone): a >= b  <=>  f2ord(a) >= f2ord(b)
__device__ __forceinline__ unsigned f2ord(float f) {
    unsigned u = __float_as_uint(f);
    return (u & 0x80000000u) ? ~u : (u | 0x80000000u);
}
__device__ __forceinline__ float ord2f(unsigned o) {
    return (o & 0x80000000u) ? __uint_as_float(o & 0x7FFFFFFFu) : __uint_as_float(~o);
}

// K0: split fp32 -> bf16 hi + bf16 lo (x ~= hi + lo to ~2^-17 rel)
__global__ void split_bf16(const float* __restrict__ x,
                           unsigned short* __restrict__ hi,
                           unsigned short* __restrict__ lo, int n4)
{
    int i = blockIdx.x * blockDim.x + threadIdx.x;
    const int stride = gridDim.x * blockDim.x;
    const float4* X4 = (const float4*)x;
    for (; i < n4; i += stride) {
        float4 v = X4[i];
        ushort4 h, l;
        float f;
        h.x = f2bf(v.x); f = v.x - __uint_as_float((unsigned)h.x << 16); l.x = f2bf(f);
        h.y = f2bf(v.y); f = v.y - __uint_as_float((unsigned)h.y << 16); l.y = f2bf(f);
        h.z = f2bf(v.z); f = v.z - __uint_as_float((unsigned)h.z << 16); l.z = f2bf(f);
        h.w = f2bf(v.w); f = v.w - __uint_as_float((unsigned)h.w << 16); l.w = f2bf(f);
        ((ushort4*)hi)[i] = h;
        ((ushort4*)lo)[i] = l;
    }
}

__global__ void zero_cnt(int* __restrict__ cnt)
{
    int i = blockIdx.x * blockDim.x + threadIdx.x;
    if (i < B_ROWS) cnt[i] = 0;
}

// SAMPLE kernel: 3-pass bf16 MFMA GEMM + exact per-(row,chunk) top-50 over the
// first `ntiles` tiles of each chunk. (Round-7-verified machinery.)
__global__ __launch_bounds__(256, 2)
void knn_mfma_topk(const unsigned short* __restrict__ fhi,
                   const unsigned short* __restrict__ flo,
                   const unsigned short* __restrict__ ahi,
                   const unsigned short* __restrict__ alo,
                   float* __restrict__ cv, int* __restrict__ ci, int ntiles)
{
    __shared__ __align__(16) unsigned char sMem[SMEM_BYTES];
    __shared__ uint2 s_top[BT][TOPK];                // SORTED top-50 (v desc, idx asc)
    __shared__ float s_rowmin[BT];
    __shared__ int   s_cnt2[BT];
    __shared__ int   s_pcnt[2][BT];
    __shared__ int   s_more[2];
    __shared__ int   s_tmprs[4][CAP];

    uint2* cand = (uint2*)sMem;

    const int tid  = threadIdx.x;
    const int w    = tid >> 6;
    const int lane = tid & 63;
    const int quad = lane >> 4;
    const int lx   = lane & 15;
    const int rbase = blockIdx.x * BT;
    const int cbase = blockIdx.y * CHUNK;

    if (tid < BT) { s_rowmin[tid] = -INFINITY; s_cnt2[tid] = 0; }

    const int tB = w * 4;
    const int frow = rbase + lane;

    for (int tile = 0; tile < ntiles; ++tile) {
        const int abase = cbase + tile * AT;
        const int valid = min(AT, cbase + CHUNK - abase);

        int garow[4];
        #pragma unroll
        for (int i = 0; i < 4; ++i) {
            int t = tB + i;
            int a = ((t & 3) << 6) + lane;
            int g = abase + a; if (g > N_ANCH - 1) g = N_ANCH - 1;
            garow[i] = g;
        }

        f32x4 acc[4][4];
        const f32x4 z = {0.f, 0.f, 0.f, 0.f};
        #pragma unroll
        for (int tm = 0; tm < 4; ++tm)
            #pragma unroll
            for (int tn = 0; tn < 4; ++tn) acc[tm][tn] = z;

        for (int c = 0; c < NCHUNK; ++c) {
            __syncthreads();
            const int kb = c * KC;
            #pragma unroll
            for (int i = 0; i < 4; ++i) {
                int t = tB + i;
                size_t goff = (size_t)garow[i] * DIM + kb + ((t >> 2) << 3);
                gl_lds16(ahi + goff, sMem + OFF_BHI + t * 1024);
                gl_lds16(alo + goff, sMem + OFF_BLO + t * 1024);
            }
            {
                size_t goff = (size_t)frow * DIM + kb + (w << 3);
                gl_lds16(fhi + goff, sMem + OFF_AHI + w * 1024);
                gl_lds16(flo + goff, sMem + OFF_ALO + w * 1024);
            }
            __syncthreads();

            bf16x8 bh[4], bl[4], ah[4], al[4];
            #pragma unroll
            for (int tn = 0; tn < 4; ++tn) {
                int a = (w << 6) + (tn << 4) + lx;
                int off = (quad << 12) + (a << 4);
                bh[tn] = *(const bf16x8*)(sMem + OFF_BHI + off);
                bl[tn] = *(const bf16x8*)(sMem + OFF_BLO + off);
            }
            #pragma unroll
            for (int tm = 0; tm < 4; ++tm) {
                int r = (tm << 4) + lx;
                int off = (quad << 10) + (r << 4);
                ah[tm] = *(const bf16x8*)(sMem + OFF_AHI + off);
                al[tm] = *(const bf16x8*)(sMem + OFF_ALO + off);
            }
            #pragma unroll
            for (int tm = 0; tm < 4; ++tm)
                #pragma unroll
                for (int tn = 0; tn < 4; ++tn) {
                    acc[tm][tn] = __builtin_amdgcn_mfma_f32_16x16x32_bf16(ah[tm], bh[tn], acc[tm][tn], 0, 0, 0);
                    acc[tm][tn] = __builtin_amdgcn_mfma_f32_16x16x32_bf16(al[tm], bh[tn], acc[tm][tn], 0, 0, 0);
                    acc[tm][tn] = __builtin_amdgcn_mfma_f32_16x16x32_bf16(ah[tm], bl[tn], acc[tm][tn], 0, 0, 0);
                }
        }

        // ---- candidate selection ----
        if (tid < BT) s_pcnt[0][tid] = 0;
        if (tid == 0) s_more[0] = 0;
        __syncthreads();

        unsigned rmask[4];
        #pragma unroll
        for (int tm = 0; tm < 4; ++tm) rmask[tm] = 0xFFFFu;

        int p = 0;
        for (int round = 0; round < 8; ++round) {
            #pragma unroll
            for (int tm = 0; tm < 4; ++tm) {
                unsigned m = rmask[tm];
                if (!m) continue;
                float rmv[4];
                #pragma unroll
                for (int reg = 0; reg < 4; ++reg)
                    rmv[reg] = s_rowmin[(tm << 4) + (quad << 2) + reg];
                #pragma unroll
                for (int tn = 0; tn < 4; ++tn) {
                    #pragma unroll
                    for (int reg = 0; reg < 4; ++reg) {
                        const unsigned bit = 1u << (tn * 4 + reg);
                        if (m & bit) {
                            const int   r    = (tm << 4) + (quad << 2) + reg;
                            const int   aoff = (w << 6) + (tn << 4) + lx;
                            const float v    = acc[tm][tn][reg];
                            if (aoff < valid && v >= rmv[reg]) {
                                int slot = atomicAdd(&s_pcnt[p][r], 1);
                                if (slot < CAP) {
                                    cand[r * CAP + slot] =
                                        make_uint2(__float_as_uint(v), (unsigned)(abase + aoff));
                                    m &= ~bit;
                                } else {
                                    s_more[p] = 1;
                                }
                            } else {
                                m &= ~bit;
                            }
                        }
                    }
                }
                rmask[tm] = m;
            }
            if (tid < BT) s_pcnt[p ^ 1][tid] = 0;
            if (tid == 0) s_more[p ^ 1] = 0;
            __syncthreads();
            const int more = s_more[p];

            for (int rr = 0; rr < 16; ++rr) {
                const int r = (w << 4) + rr;
                int cnt = s_pcnt[p][r]; if (cnt > CAP) cnt = CAP;
                if (cnt == 0) continue;
                const int k0   = s_cnt2[r];
                const int pool = k0 + cnt;

                uint2 myc = cand[r * CAP + lane];
                float vc = __uint_as_float(myc.x); int icd = (int)myc.y;
                uint2 mys = s_top[r][lane < TOPK ? lane : TOPK - 1];
                float vs = __uint_as_float(mys.x); int isd = (int)mys.y;

                int rc = 0;
                for (int q = 0; q < cnt; ++q) {
                    uint2 cq = cand[r * CAP + q];
                    float vq = __uint_as_float(cq.x); int iq = (int)cq.y;
                    rc += lex_better(vq, iq, vc, icd);
                }
                int lo = 0, hi = k0;
                #pragma unroll
                for (int it = 0; it < 7; ++it) {
                    int mid = (lo + hi) >> 1;
                    uint2 t = s_top[r][mid < TOPK ? mid : TOPK - 1];
                    bool b  = lex_better(__uint_as_float(t.x), (int)t.y, vc, icd);
                    bool go = lo < hi;
                    lo = (go && b)  ? mid + 1 : lo;
                    hi = (go && !b) ? mid : hi;
                }
                const int rs = lo;
                const int fc = rc + rs;

                if (lane < cnt) s_tmprs[w][rc] = rs;
                asm volatile("s_waitcnt lgkmcnt(0)" ::: "memory");
                int lo2 = 0, hi2 = cnt;
                #pragma unroll
                for (int it = 0; it < 7; ++it) {
                    int mid = (lo2 + hi2) >> 1;
                    int rv  = s_tmprs[w][mid < CAP ? mid : CAP - 1];
                    bool b  = (rv <= lane);
                    bool go = lo2 < hi2;
                    lo2 = (go && b)  ? mid + 1 : lo2;
                    hi2 = (go && !b) ? mid : hi2;
                }
                const int fs = lane + lo2;

                if (lane < cnt && fc < TOPK) s_top[r][fc] = myc;
                if (lane < k0  && fs < TOPK) s_top[r][fs] = mys;
                if (lane < cnt && fc == TOPK - 1) s_rowmin[r] = vc;
                if (lane < k0  && fs == TOPK - 1) s_rowmin[r] = vs;
                if (lane == 0) s_cnt2[r] = (pool < TOPK) ? pool : TOPK;
            }
            __syncthreads();
            if (!more) break;
            p ^= 1;
        }
    }
    __syncthreads();
    for (int e = tid; e < BT * TOPK; e += 256) {
        int row = e / TOPK, j = e % TOPK;
        uint2 cc = s_top[row][j];
        size_t g = ((size_t)(rbase + row) * NCH + blockIdx.y) * TOPK + j;
        cv[g] = __uint_as_float(cc.x);
        ci[g] = (int)cc.y;
    }
}

// KT: bisection threshold. T[row] = value with count(sample >= T) in [50, 64]
// (invariant count >= 50 => T <= sample 50th <= true 50th; clo<=64 bounds appends).
__global__ __launch_bounds__(256)
void thresh50(const float* __restrict__ cv, float* __restrict__ Tarr)
{
    const int M = NCH * TOPK;   // 800
    __shared__ float sv[NCH * TOPK];
    __shared__ float s_rmin[4], s_rmax[4];
    __shared__ int   s_c;
    const int row = blockIdx.x;
    const int tid = threadIdx.x;
    const int lane = tid & 63, w = tid >> 6;

    for (int e0 = 0; e0 < M; e0 += 256) {
        int e = e0 + tid;
        if (e < M) sv[e] = cv[(size_t)row * M + e];
    }
    __syncthreads();
    // block min/max
    float lmin = INFINITY, lmax = -INFINITY;
    for (int e0 = 0; e0 < M; e0 += 256) {
        int e = e0 + tid;
        if (e < M) { float v = sv[e]; lmin = fminf(lmin, v); lmax = fmaxf(lmax, v); }
    }
    #pragma unroll
    for (int off = 32; off; off >>= 1) {
        lmin = fminf(lmin, __shfl_down(lmin, off));
        lmax = fmaxf(lmax, __shfl_down(lmax, off));
    }
    if (lane == 0) { s_rmin[w] = lmin; s_rmax[w] = lmax; }
    __syncthreads();
    float lo = fminf(fminf(s_rmin[0], s_rmin[1]), fminf(s_rmin[2], s_rmin[3]));
    float mx = fmaxf(fmaxf(s_rmax[0], s_rmax[1]), fmaxf(s_rmax[2], s_rmax[3]));
    float hi = ord2f(f2ord(mx) + 1);   // count(>= hi) == 0
    int clo = M;
    for (int it = 0; it < 32 && clo > 64; ++it) {
        float mid = 0.5f * (lo + hi);
        if (tid == 0) s_c = 0;
        __syncthreads();
        int lc = 0;
        for (int e0 = 0; e0 < M; e0 += 256) {
            int e = e0 + tid;
            lc += (e < M && sv[e] >= mid);
        }
        #pragma unroll
        for (int off = 32; off; off >>= 1) lc += __shfl_down(lc, off);
        if (lane == 0) atomicAdd(&s_c, lc);
        __syncthreads();
        int c = s_c;
        if (c >= TOPK) { lo = mid; clo = c; } else hi = mid;
        __syncthreads();   // before next iter's s_c reset
    }
    if (tid == 0) Tarr[row] = lo;
}

// APPEND kernel: pure 3-pass MFMA GEMM over 4 tiles (grid.z picks the group);
// per element threshold-test and append to the row's global list.
__global__ __launch_bounds__(256, 3)
void knn_mfma_append(const unsigned short* __restrict__ fhi,
                     const unsigned short* __restrict__ flo,
                     const unsigned short* __restrict__ ahi,
                     const unsigned short* __restrict__ alo,
                     const float* __restrict__ Tarr,
                     uint2* __restrict__ cand, int* __restrict__ cnt)
{
    __shared__ __align__(16) unsigned char sMem[SMEM_BYTES];
    __shared__ float s_T[BT];

    const int tid  = threadIdx.x;
    const int w    = tid >> 6;
    const int lane = tid & 63;
    const int quad = lane >> 4;
    const int lx   = lane & 15;
    const int rbase = blockIdx.x * BT;
    const int cbase = blockIdx.y * CHUNK;
    const int t0 = 1 + 4 * blockIdx.z;      // tiles [t0, t0+4) of 1..12

    if (tid < BT) s_T[tid] = Tarr[rbase + tid];
    __syncthreads();
    float thr[4][4];
    #pragma unroll
    for (int tm = 0; tm < 4; ++tm)
        #pragma unroll
        for (int reg = 0; reg < 4; ++reg)
            thr[tm][reg] = s_T[(tm << 4) + (quad << 2) + reg];

    const int tB = w * 4;
    const int frow = rbase + lane;

    for (int tile = t0; tile < t0 + 4; ++tile) {
        const int abase = cbase + tile * AT;
        const int valid = min(AT, cbase + CHUNK - abase);   // tail tile: 53

        int garow[4];
        #pragma unroll
        for (int i = 0; i < 4; ++i) {
            int t = tB + i;
            int a = ((t & 3) << 6) + lane;
            int g = abase + a; if (g > N_ANCH - 1) g = N_ANCH - 1;
            garow[i] = g;
        }

        f32x4 acc[4][4];
        const f32x4 z = {0.f, 0.f, 0.f, 0.f};
        #pragma unroll
        for (int tm = 0; tm < 4; ++tm)
            #pragma unroll
            for (int tn = 0; tn < 4; ++tn) acc[tm][tn] = z;

        for (int c = 0; c < NCHUNK; ++c) {
            __syncthreads();
            const int kb = c * KC;
            #pragma unroll
            for (int i = 0; i < 4; ++i) {
                int t = tB + i;
                size_t goff = (size_t)garow[i] * DIM + kb + ((t >> 2) << 3);
                gl_lds16(ahi + goff, sMem + OFF_BHI + t * 1024);
                gl_lds16(alo + goff, sMem + OFF_BLO + t * 1024);
            }
            {
                size_t goff = (size_t)frow * DIM + kb + (w << 3);
                gl_lds16(fhi + goff, sMem + OFF_AHI + w * 1024);
                gl_lds16(flo + goff, sMem + OFF_ALO + w * 1024);
            }
            __syncthreads();

            bf16x8 bh[4], bl[4], ah[4], al[4];
            #pragma unroll
            for (int tn = 0; tn < 4; ++tn) {
                int a = (w << 6) + (tn << 4) + lx;
                int off = (quad << 12) + (a << 4);
                bh[tn] = *(const bf16x8*)(sMem + OFF_BHI + off);
                bl[tn] = *(const bf16x8*)(sMem + OFF_BLO + off);
            }
            #pragma unroll
            for (int tm = 0; tm < 4; ++tm) {
                int r = (tm << 4) + lx;
                int off = (quad << 10) + (r << 4);
                ah[tm] = *(const bf16x8*)(sMem + OFF_AHI + off);
                al[tm] = *(const bf16x8*)(sMem + OFF_ALO + off);
            }
            #pragma unroll
            for (int tm = 0; tm < 4; ++tm)
                #pragma unroll
                for (int tn = 0; tn < 4; ++tn) {
                    acc[tm][tn] = __builtin_amdgcn_mfma_f32_16x16x32_bf16(ah[tm], bh[tn], acc[tm][tn], 0, 0, 0);
                    acc[tm][tn] = __builtin_amdgcn_mfma_f32_16x16x32_bf16(al[tm], bh[tn], acc[tm][tn], 0, 0, 0);
                    acc[tm][tn] = __builtin_amdgcn_mfma_f32_16x16x32_bf16(ah[tm], bl[tn], acc[tm][tn], 0, 0, 0);
                }
        }

        // threshold-filtered global append (C/D: row = 16tm+4quad+reg, col = 64w+16tn+lx)
        #pragma unroll
        for (int tm = 0; tm < 4; ++tm)
            #pragma unroll
            for (int tn = 0; tn < 4; ++tn)
                #pragma unroll
                for (int reg = 0; reg < 4; ++reg) {
                    const float v    = acc[tm][tn][reg];
                    const int   aoff = (w << 6) + (tn << 4) + lx;
                    if (aoff < valid && v >= thr[tm][reg]) {
                        const int row = rbase + (tm << 4) + (quad << 2) + reg;
                        int slot = atomicAdd(&cnt[row], 1);
                        if (slot < CAPG)
                            cand[(size_t)row * CAPG + slot] =
                                make_uint2(__float_as_uint(v), (unsigned)(abase + aoff));
                    }
                }
    }
}

// FINAL: pool = (cv >= T) U appended; bisect to T2 (count in [50,96]); exact
// lex rank-scan of survivors only. Fallback full scan if bisection won't tighten.
__global__ __launch_bounds__(256)
void knn_final(const float* __restrict__ cv, const int* __restrict__ ci,
               const uint2* __restrict__ cand, const int* __restrict__ cnt,
               const float* __restrict__ Tarr,
               const int* __restrict__ labels, const int* __restrict__ anchor_label,
               float* __restrict__ out)
{
    const int M = NCH * TOPK;   // 800
    __shared__ float pv[NCH*TOPK + CAPG];
    __shared__ int   pi[NCH*TOPK + CAPG];
    __shared__ float fv[128];
    __shared__ int   fi[128];
    __shared__ float s_rmin[4], s_rmax[4];
    __shared__ int   s_ns, s_c, s_m, s_cm;
    __shared__ float s_sum;

    const int row = blockIdx.x;
    const int tid = threadIdx.x;
    const int lane = tid & 63, w = tid >> 6;
    const unsigned long long lmask = (lane == 63) ? 0xFFFFFFFFFFFFFFFFull >> 1 << 1 >> 0
                                                  : ((1ull << lane) - 1ull);
    // (lane 63: mask of lanes < 63) -- computed branch-free below instead
    const unsigned long long below = (lane == 0) ? 0ull : (~0ull >> (64 - lane));

    if (tid == 0) { s_ns = 0; s_sum = 0.f; s_cm = 0; }
    __syncthreads();

    const float T = Tarr[row];
    // compact cv entries >= T (ballot compaction: 1 atomic per wave per strip)
    for (int e0 = 0; e0 < M; e0 += 256) {
        int e = e0 + tid;
        float v = (e < M) ? cv[(size_t)row * M + e] : -INFINITY;
        int   id = (e < M) ? ci[(size_t)row * M + e] : 0;
        bool pred = (e < M) && (v >= T);
        unsigned long long mk = __ballot(pred);
        int base = 0;
        if (lane == 0) base = atomicAdd(&s_ns, __popcll(mk));
        base = __shfl(base, 0);
        if (pred) {
            int ofs = base + __popcll(mk & below);
            pv[ofs] = v; pi[ofs] = id;
        }
    }
    int cr = cnt[row]; if (cr > CAPG) cr = CAPG;
    for (int e0 = 0; e0 < cr; e0 += 256) {
        int e = e0 + tid;
        bool pred = (e < cr);
        uint2 c = pred ? cand[(size_t)row * CAPG + e] : make_uint2(0u, 0u);
        unsigned long long mk = __ballot(pred);
        int base = 0;
        if (lane == 0) base = atomicAdd(&s_ns, __popcll(mk));
        base = __shfl(base, 0);
        if (pred) {
            int ofs = base + __popcll(mk & below);
            pv[ofs] = __uint_as_float(c.x); pi[ofs] = (int)c.y;
        }
    }
    __syncthreads();
    const int ns = s_ns;             // >= 50 guaranteed
    const int mylab = labels[row];

    // block min/max over pool
    float lmin = INFINITY, lmax = -INFINITY;
    for (int e0 = 0; e0 < ns; e0 += 256) {
        int e = e0 + tid;
        if (e < ns) { float v = pv[e]; lmin = fminf(lmin, v); lmax = fmaxf(lmax, v); }
    }
    #pragma unroll
    for (int off = 32; off; off >>= 1) {
        lmin = fminf(lmin, __shfl_down(lmin, off));
        lmax = fmaxf(lmax, __shfl_down(lmax, off));
    }
    if (lane == 0) { s_rmin[w] = lmin; s_rmax[w] = lmax; }
    __syncthreads();
    float lo = fminf(fminf(s_rmin[0], s_rmin[1]), fminf(s_rmin[2], s_rmin[3]));
    float mx = fmaxf(fmaxf(s_rmax[0], s_rmax[1]), fmaxf(s_rmax[2], s_rmax[3]));
    float hi = ord2f(f2ord(mx) + 1);
    int clo = ns;
    for (int it = 0; it < 32 && clo > 96; ++it) {
        float mid = 0.5f * (lo + hi);
        if (tid == 0) s_c = 0;
        __syncthreads();
        int lc = 0;
        for (int e0 = 0; e0 < ns; e0 += 256) {
            int e = e0 + tid;
            lc += (e < ns && pv[e] >= mid);
        }
        #pragma unroll
        for (int off = 32; off; off >>= 1) lc += __shfl_down(lc, off);
        if (lane == 0) atomicAdd(&s_c, lc);
        __syncthreads();
        int c = s_c;
        if (c >= TOPK) { lo = mid; clo = c; } else hi = mid;
        __syncthreads();
    }

    if (clo <= 96) {
        // compact survivors (>= lo); elements below lo are provably outside top-50
        if (tid == 0) s_m = 0;
        __syncthreads();
        for (int e0 = 0; e0 < ns; e0 += 256) {
            int e = e0 + tid;
            bool pred = (e < ns) && (pv[e] >= lo);
            unsigned long long mk = __ballot(pred);
            int base = 0;
            if (lane == 0) base = atomicAdd(&s_m, __popcll(mk));
            base = __shfl(base, 0);
            if (pred) {
                int ofs = base + __popcll(mk & below);
                fv[ofs] = pv[e]; fi[ofs] = pi[e];
            }
        }
        __syncthreads();
        const int m = s_m;           // == clo, in [50,96]
        if (tid < m) {
            float v = fv[tid]; int id = fi[tid];
            int r = 0;
            for (int q = 0; q < m; ++q) {
                float vq = fv[q];
                r += (vq > v) || (vq == v && fi[q] < id);
            }
            if (r < TOPK) {
                atomicAdd(&s_sum, v);
                if (anchor_label[id] == mylab) atomicAdd(&s_cm, 1);
            }
        }
    } else {
        // fallback: full exact rank scan (pathological value clustering only)
        for (int e0 = 0; e0 < ns; e0 += 256) {
            int e = e0 + tid;
            if (e < ns) {
                float v = pv[e]; int id = pi[e];
                int r = 0;
                for (int q = 0; q < ns; ++q) {
                    float vq = pv[q];
                    r += (vq > v) || (vq == v && pi[q] < id);
                }
                if (r < TOPK) {
                    atomicAdd(&s_sum, v);
                    if (anchor_label[id] == mylab) atomicAdd(&s_cm, 1);
                }
            }
        }
    }
    __syncthreads();
    if (tid == 0) {
        float mlp = (float)s_cm / (float)TOPK;
        out[row]          = -mlp;                 // loss
        out[B_ROWS + row] = s_sum / (float)TOPK;  // mean_sim
    }
}

extern "C" void kernel_launch(void* const* d_in, const int* in_sizes, int n_in,
                              void* d_out, int out_size, void* d_ws, size_t ws_size,
                              hipStream_t stream)
{
    const float* feat         = (const float*)d_in[0];
    const float* anc          = (const float*)d_in[1];
    const int*   labels       = (const int*)d_in[2];
    // d_in[3] = t_labels (unused)
    const int*   anchor_label = (const int*)d_in[4];
    float* out = (float*)d_out;

    char* ws = (char*)d_ws;
    size_t off = 0;
    float* cv = (float*)(ws + off);          off += (size_t)B_ROWS * NCH * TOPK * 4;    // 6.55 MB
    int*   ci = (int*)(ws + off);            off += (size_t)B_ROWS * NCH * TOPK * 4;    // 6.55 MB
    unsigned short* fhi = (unsigned short*)(ws + off); off += (size_t)B_ROWS * DIM * 2; // 1.05 MB
    unsigned short* flo = (unsigned short*)(ws + off); off += (size_t)B_ROWS * DIM * 2;
    unsigned short* ahi = (unsigned short*)(ws + off); off += (size_t)N_ANCH * DIM * 2; // 25.6 MB
    unsigned short* alo = (unsigned short*)(ws + off); off += (size_t)N_ANCH * DIM * 2; // 25.6 MB
    uint2* cand = (uint2*)(ws + off);        off += (size_t)B_ROWS * CAPG * 8;          // 16.8 MB
    int*   cnt  = (int*)(ws + off);          off += (size_t)B_ROWS * 4;
    float* Tarr = (float*)(ws + off);        off += (size_t)B_ROWS * 4;                 // total ~83 MB

    hipLaunchKernelGGL(split_bf16, dim3(256), dim3(256), 0, stream,
                       feat, fhi, flo, B_ROWS * DIM / 4);
    hipLaunchKernelGGL(split_bf16, dim3(4096), dim3(256), 0, stream,
                       anc, ahi, alo, N_ANCH * DIM / 4);
    hipLaunchKernelGGL(zero_cnt, dim3(8), dim3(256), 0, stream, cnt);
    hipLaunchKernelGGL(knn_mfma_topk, dim3(B_ROWS / BT, NCH), dim3(256), 0, stream,
                       fhi, flo, ahi, alo, cv, ci, 1);          // sample: tile 0 only
    hipLaunchKernelGGL(thresh50, dim3(B_ROWS), dim3(256), 0, stream, cv, Tarr);
    hipLaunchKernelGGL(knn_mfma_append, dim3(B_ROWS / BT, NCH, 3), dim3(256), 0, stream,
                       fhi, flo, ahi, alo, Tarr, cand, cnt);    // tiles 1..12, z-split
    hipLaunchKernelGGL(knn_final, dim3(B_ROWS), dim3(256), 0, stream,
                       cv, ci, cand, cnt, Tarr, labels, anchor_label, out);
}

// Round 10
// 967.881 us; speedup vs baseline: 15.5912x; 1.1107x over previous
//
#include <hip/hip_runtime.h>
#include <math.h>

// Problem constants (match setup_inputs)
#define B_ROWS 2048
#define N_ANCH 50000
#define DIM    256
#define TOPK   50

// Tiling
#define BT 64          // feature rows per block
#define AT 256         // anchors per tile (4 waves x 64)
#define KC 32          // k per staged chunk (= one MFMA K)
#define NCHUNK 8       // DIM/KC
#define NCH 16         // anchor chunks (50000/16 = 3125)
#define CHUNK 3125
#define NTILES 13      // ceil(3125/256)
#define NSAMP 4096     // sample anchors per row (tile 0 of each chunk)
#define CAPG 2048      // per-row candidate capacity (overlays the 16KB sims row slice)

typedef __attribute__((ext_vector_type(8))) short bf16x8;   // 8 bf16 in 4 VGPRs
typedef __attribute__((ext_vector_type(4))) float f32x4;

// LDS layout for the pass-split GEMM (20.25 KB)
#define OFF_B 0            // anchors: slot = kq*256 + a, 16B/slot -> 16 KB
#define OFF_A 16384        // feats:   slot = kq*64  + r, 16B/slot -> 4 KB
#define SMEM_BYTES 20480

__device__ __forceinline__ void gl_lds16(const void* g, void* l) {
    // async global->LDS, 16B/lane; LDS dest = uniform base + lane*16
    __builtin_amdgcn_global_load_lds(
        (const __attribute__((address_space(1))) unsigned int*)g,
        (__attribute__((address_space(3))) unsigned int*)l, 16, 0, 0);
}

__device__ __forceinline__ unsigned short f2bf(float x) {
    unsigned u = __float_as_uint(x);
    u += 0x7FFFu + ((u >> 16) & 1u);             // RNE
    return (unsigned short)(u >> 16);
}

// ordered-uint mapping for float (monotone)
__device__ __forceinline__ unsigned f2ord(float f) {
    unsigned u = __float_as_uint(f);
    return (u & 0x80000000u) ? ~u : (u | 0x80000000u);
}
__device__ __forceinline__ float ord2f(unsigned o) {
    return (o & 0x80000000u) ? __uint_as_float(o & 0x7FFFFFFFu) : __uint_as_float(~o);
}

// K0: split fp32 -> bf16 hi + bf16 lo (x ~= hi + lo to ~2^-17 rel)
__global__ void split_bf16(const float* __restrict__ x,
                           unsigned short* __restrict__ hi,
                           unsigned short* __restrict__ lo, int n4)
{
    int i = blockIdx.x * blockDim.x + threadIdx.x;
    const int stride = gridDim.x * blockDim.x;
    const float4* X4 = (const float4*)x;
    for (; i < n4; i += stride) {
        float4 v = X4[i];
        ushort4 h, l;
        float f;
        h.x = f2bf(v.x); f = v.x - __uint_as_float((unsigned)h.x << 16); l.x = f2bf(f);
        h.y = f2bf(v.y); f = v.y - __uint_as_float((unsigned)h.y << 16); l.y = f2bf(f);
        h.z = f2bf(v.z); f = v.z - __uint_as_float((unsigned)h.z << 16); l.z = f2bf(f);
        h.w = f2bf(v.w); f = v.w - __uint_as_float((unsigned)h.w << 16); l.w = f2bf(f);
        ((ushort4*)hi)[i] = h;
        ((ushort4*)lo)[i] = l;
    }
}

// SAMPLE GEMM: pass-split 3-pass bf16 MFMA over tile 0 of each chunk;
// writes raw fp32 sims[row][chunk*256 + col]. No selection.
__global__ __launch_bounds__(256, 4)
void knn_sample_gemm(const unsigned short* __restrict__ fhi,
                     const unsigned short* __restrict__ flo,
                     const unsigned short* __restrict__ ahi,
                     const unsigned short* __restrict__ alo,
                     float* __restrict__ sims)
{
    __shared__ __align__(16) unsigned char sMem[SMEM_BYTES];

    const int tid  = threadIdx.x;
    const int w    = tid >> 6;
    const int lane = tid & 63;
    const int quad = lane >> 4;
    const int lx   = lane & 15;
    const int rbase = blockIdx.x * BT;
    const int abase = blockIdx.y * CHUNK;        // tile 0 of this chunk (all 256 valid)

    const int tB = w * 4;
    const int frow = rbase + lane;

    int garow[4];
    #pragma unroll
    for (int i = 0; i < 4; ++i) {
        int t = tB + i;
        garow[i] = abase + ((t & 3) << 6) + lane;
    }

    f32x4 acc[4][4];
    const f32x4 z = {0.f, 0.f, 0.f, 0.f};
    #pragma unroll
    for (int tm = 0; tm < 4; ++tm)
        #pragma unroll
        for (int tn = 0; tn < 4; ++tn) acc[tm][tn] = z;

    const unsigned short* Ap[3] = {fhi, flo, fhi};
    const unsigned short* Bp[3] = {ahi, ahi, alo};

    for (int p = 0; p < 3; ++p) {
        const unsigned short* Asrc = Ap[p];
        const unsigned short* Bsrc = Bp[p];
        for (int c = 0; c < NCHUNK; ++c) {
            __syncthreads();
            const int kb = c * KC;
            #pragma unroll
            for (int i = 0; i < 4; ++i) {
                int t = tB + i;
                gl_lds16(Bsrc + (size_t)garow[i] * DIM + kb + ((t >> 2) << 3),
                         sMem + OFF_B + t * 1024);
            }
            gl_lds16(Asrc + (size_t)frow * DIM + kb + (w << 3), sMem + OFF_A + w * 1024);
            __syncthreads();

            bf16x8 bf[4], af[4];
            #pragma unroll
            for (int tn = 0; tn < 4; ++tn) {
                int a = (w << 6) + (tn << 4) + lx;
                bf[tn] = *(const bf16x8*)(sMem + OFF_B + (quad << 12) + (a << 4));
            }
            #pragma unroll
            for (int tm = 0; tm < 4; ++tm) {
                int r = (tm << 4) + lx;
                af[tm] = *(const bf16x8*)(sMem + OFF_A + (quad << 10) + (r << 4));
            }
            #pragma unroll
            for (int tm = 0; tm < 4; ++tm)
                #pragma unroll
                for (int tn = 0; tn < 4; ++tn)
                    acc[tm][tn] = __builtin_amdgcn_mfma_f32_16x16x32_bf16(af[tm], bf[tn], acc[tm][tn], 0, 0, 0);
        }
    }

    // C/D layout: row = 16tm + 4quad + reg, col = 64w + 16tn + lx
    #pragma unroll
    for (int tm = 0; tm < 4; ++tm)
        #pragma unroll
        for (int tn = 0; tn < 4; ++tn)
            #pragma unroll
            for (int reg = 0; reg < 4; ++reg) {
                int row = rbase + (tm << 4) + (quad << 2) + reg;
                int col = (w << 6) + (tn << 4) + lx;
                sims[(size_t)row * NSAMP + blockIdx.y * AT + col] = acc[tm][tn][reg];
            }
}

// BISECT: per row, T = value with count(sample >= T) in [50,64] (=> T <= true 50th);
// appends sample survivors to cand (overlaid on the row's own sims), sets cnt.
__global__ __launch_bounds__(256)
void bisect_thresh(const float* __restrict__ sims,
                   uint2* __restrict__ cand, int* __restrict__ cnt,
                   float* __restrict__ Tarr)
{
    __shared__ float sv[NSAMP];                  // 16 KB
    __shared__ float s_rmin[4], s_rmax[4];
    __shared__ int   s_c, s_ns;

    const int row = blockIdx.x;
    const int tid = threadIdx.x;
    const int lane = tid & 63, w = tid >> 6;
    const unsigned long long below = (lane == 0) ? 0ull : (~0ull >> (64 - lane));

    // load row sims into LDS FIRST (cand overlay safety: all reads precede writes)
    const float4* S4 = (const float4*)(sims + (size_t)row * NSAMP);
    for (int i = tid; i < NSAMP / 4; i += 256) ((float4*)sv)[i] = S4[i];
    __syncthreads();

    float lmin = INFINITY, lmax = -INFINITY;
    for (int e0 = 0; e0 < NSAMP; e0 += 256) {
        float v = sv[e0 + tid];
        lmin = fminf(lmin, v); lmax = fmaxf(lmax, v);
    }
    #pragma unroll
    for (int off = 32; off; off >>= 1) {
        lmin = fminf(lmin, __shfl_down(lmin, off));
        lmax = fmaxf(lmax, __shfl_down(lmax, off));
    }
    if (lane == 0) { s_rmin[w] = lmin; s_rmax[w] = lmax; }
    __syncthreads();
    float lo = fminf(fminf(s_rmin[0], s_rmin[1]), fminf(s_rmin[2], s_rmin[3]));
    float mx = fmaxf(fmaxf(s_rmax[0], s_rmax[1]), fmaxf(s_rmax[2], s_rmax[3]));
    float hi = ord2f(f2ord(mx) + 1);             // count(>= hi) == 0
    int clo = NSAMP;
    for (int it = 0; it < 32 && clo > 64; ++it) {
        float mid = 0.5f * (lo + hi);
        if (tid == 0) s_c = 0;
        __syncthreads();
        int lc = 0;
        for (int e0 = 0; e0 < NSAMP; e0 += 256) lc += (sv[e0 + tid] >= mid);
        #pragma unroll
        for (int off = 32; off; off >>= 1) lc += __shfl_down(lc, off);
        if (lane == 0) atomicAdd(&s_c, lc);
        __syncthreads();
        int c = s_c;
        if (c >= TOPK) { lo = mid; clo = c; } else hi = mid;
        __syncthreads();
    }
    if (tid == 0) { Tarr[row] = lo; s_ns = 0; }
    __syncthreads();

    // append survivors (v >= lo): ballot compaction, anchor = chunk*3125 + a
    for (int e0 = 0; e0 < NSAMP; e0 += 256) {
        int e = e0 + tid;
        float v = sv[e];
        bool pred = (v >= lo);
        unsigned long long mk = __ballot(pred);
        int base = 0;
        if (lane == 0) base = atomicAdd(&s_ns, __popcll(mk));
        base = __shfl(base, 0);
        if (pred) {
            int ofs = base + __popcll(mk & below);
            int anchor = (e >> 8) * CHUNK + (e & 255);
            cand[(size_t)row * CAPG + ofs] = make_uint2(__float_as_uint(v), (unsigned)anchor);
        }
    }
    __syncthreads();
    if (tid == 0) cnt[row] = s_ns;               // direct write: no zero_cnt needed
}

// APPEND: pass-split 3-pass MFMA GEMM over 4 tiles (grid.z picks group, tiles 1..12);
// per element threshold-test and append to the row's global list.
__global__ __launch_bounds__(256, 4)
void knn_mfma_append(const unsigned short* __restrict__ fhi,
                     const unsigned short* __restrict__ flo,
                     const unsigned short* __restrict__ ahi,
                     const unsigned short* __restrict__ alo,
                     const float* __restrict__ Tarr,
                     uint2* __restrict__ cand, int* __restrict__ cnt)
{
    __shared__ __align__(16) unsigned char sMem[SMEM_BYTES];
    __shared__ float s_T[BT];

    const int tid  = threadIdx.x;
    const int w    = tid >> 6;
    const int lane = tid & 63;
    const int quad = lane >> 4;
    const int lx   = lane & 15;
    const int rbase = blockIdx.x * BT;
    const int cbase = blockIdx.y * CHUNK;
    const int t0 = 1 + 4 * blockIdx.z;           // tiles [t0, t0+4) of 1..12

    if (tid < BT) s_T[tid] = Tarr[rbase + tid];
    __syncthreads();
    float thr[4][4];
    #pragma unroll
    for (int tm = 0; tm < 4; ++tm)
        #pragma unroll
        for (int reg = 0; reg < 4; ++reg)
            thr[tm][reg] = s_T[(tm << 4) + (quad << 2) + reg];

    const int tB = w * 4;
    const int frow = rbase + lane;
    const unsigned short* Ap[3] = {fhi, flo, fhi};
    const unsigned short* Bp[3] = {ahi, ahi, alo};

    for (int tile = t0; tile < t0 + 4; ++tile) {
        const int abase = cbase + tile * AT;
        const int valid = min(AT, cbase + CHUNK - abase);   // tail tile: 53

        int garow[4];
        #pragma unroll
        for (int i = 0; i < 4; ++i) {
            int t = tB + i;
            int g = abase + ((t & 3) << 6) + lane;
            if (g > N_ANCH - 1) g = N_ANCH - 1;             // clamp; masked below
            garow[i] = g;
        }

        f32x4 acc[4][4];
        const f32x4 z = {0.f, 0.f, 0.f, 0.f};
        #pragma unroll
        for (int tm = 0; tm < 4; ++tm)
            #pragma unroll
            for (int tn = 0; tn < 4; ++tn) acc[tm][tn] = z;

        for (int p = 0; p < 3; ++p) {
            const unsigned short* Asrc = Ap[p];
            const unsigned short* Bsrc = Bp[p];
            for (int c = 0; c < NCHUNK; ++c) {
                __syncthreads();
                const int kb = c * KC;
                #pragma unroll
                for (int i = 0; i < 4; ++i) {
                    int t = tB + i;
                    gl_lds16(Bsrc + (size_t)garow[i] * DIM + kb + ((t >> 2) << 3),
                             sMem + OFF_B + t * 1024);
                }
                gl_lds16(Asrc + (size_t)frow * DIM + kb + (w << 3), sMem + OFF_A + w * 1024);
                __syncthreads();

                bf16x8 bf[4], af[4];
                #pragma unroll
                for (int tn = 0; tn < 4; ++tn) {
                    int a = (w << 6) + (tn << 4) + lx;
                    bf[tn] = *(const bf16x8*)(sMem + OFF_B + (quad << 12) + (a << 4));
                }
                #pragma unroll
                for (int tm = 0; tm < 4; ++tm) {
                    int r = (tm << 4) + lx;
                    af[tm] = *(const bf16x8*)(sMem + OFF_A + (quad << 10) + (r << 4));
                }
                #pragma unroll
                for (int tm = 0; tm < 4; ++tm)
                    #pragma unroll
                    for (int tn = 0; tn < 4; ++tn)
                        acc[tm][tn] = __builtin_amdgcn_mfma_f32_16x16x32_bf16(af[tm], bf[tn], acc[tm][tn], 0, 0, 0);
            }
        }

        // threshold-filtered global append (C/D: row = 16tm+4quad+reg, col = 64w+16tn+lx)
        #pragma unroll
        for (int tm = 0; tm < 4; ++tm)
            #pragma unroll
            for (int tn = 0; tn < 4; ++tn)
                #pragma unroll
                for (int reg = 0; reg < 4; ++reg) {
                    const float v    = acc[tm][tn][reg];
                    const int   aoff = (w << 6) + (tn << 4) + lx;
                    if (aoff < valid && v >= thr[tm][reg]) {
                        const int row = rbase + (tm << 4) + (quad << 2) + reg;
                        int slot = atomicAdd(&cnt[row], 1);
                        if (slot < CAPG)
                            cand[(size_t)row * CAPG + slot] =
                                make_uint2(__float_as_uint(v), (unsigned)(abase + aoff));
                    }
                }
    }
}

// FINAL: pool = cand[row][0..cnt); bisect to T2 (count in [50,96]); exact lex
// rank-scan of survivors. Fallback full scan if bisection won't tighten.
__global__ __launch_bounds__(256)
void knn_final(const uint2* __restrict__ cand, const int* __restrict__ cnt,
               const int* __restrict__ labels, const int* __restrict__ anchor_label,
               float* __restrict__ out)
{
    __shared__ float pv[CAPG];
    __shared__ int   pi[CAPG];
    __shared__ float fv[128];
    __shared__ int   fi[128];
    __shared__ float s_rmin[4], s_rmax[4];
    __shared__ int   s_c, s_m, s_cm;
    __shared__ float s_sum;

    const int row = blockIdx.x;
    const int tid = threadIdx.x;
    const int lane = tid & 63, w = tid >> 6;
    const unsigned long long below = (lane == 0) ? 0ull : (~0ull >> (64 - lane));

    if (tid == 0) { s_sum = 0.f; s_cm = 0; }

    int ns = cnt[row]; if (ns > CAPG) ns = CAPG;
    for (int e0 = 0; e0 < ns; e0 += 256) {
        int e = e0 + tid;
        if (e < ns) {
            uint2 c = cand[(size_t)row * CAPG + e];
            pv[e] = __uint_as_float(c.x); pi[e] = (int)c.y;
        }
    }
    __syncthreads();
    const int mylab = labels[row];

    // block min/max over pool
    float lmin = INFINITY, lmax = -INFINITY;
    for (int e0 = 0; e0 < ns; e0 += 256) {
        int e = e0 + tid;
        if (e < ns) { float v = pv[e]; lmin = fminf(lmin, v); lmax = fmaxf(lmax, v); }
    }
    #pragma unroll
    for (int off = 32; off; off >>= 1) {
        lmin = fminf(lmin, __shfl_down(lmin, off));
        lmax = fmaxf(lmax, __shfl_down(lmax, off));
    }
    if (lane == 0) { s_rmin[w] = lmin; s_rmax[w] = lmax; }
    __syncthreads();
    float lo = fminf(fminf(s_rmin[0], s_rmin[1]), fminf(s_rmin[2], s_rmin[3]));
    float mx = fmaxf(fmaxf(s_rmax[0], s_rmax[1]), fmaxf(s_rmax[2], s_rmax[3]));
    float hi = ord2f(f2ord(mx) + 1);
    int clo = ns;
    for (int it = 0; it < 32 && clo > 96; ++it) {
        float mid = 0.5f * (lo + hi);
        if (tid == 0) s_c = 0;
        __syncthreads();
        int lc = 0;
        for (int e0 = 0; e0 < ns; e0 += 256) {
            int e = e0 + tid;
            lc += (e < ns && pv[e] >= mid);
        }
        #pragma unroll
        for (int off = 32; off; off >>= 1) lc += __shfl_down(lc, off);
        if (lane == 0) atomicAdd(&s_c, lc);
        __syncthreads();
        int c = s_c;
        if (c >= TOPK) { lo = mid; clo = c; } else hi = mid;
        __syncthreads();
    }

    if (clo <= 96) {
        if (tid == 0) s_m = 0;
        __syncthreads();
        for (int e0 = 0; e0 < ns; e0 += 256) {
            int e = e0 + tid;
            bool pred = (e < ns) && (pv[e] >= lo);
            unsigned long long mk = __ballot(pred);
            int base = 0;
            if (lane == 0) base = atomicAdd(&s_m, __popcll(mk));
            base = __shfl(base, 0);
            if (pred) {
                int ofs = base + __popcll(mk & below);
                fv[ofs] = pv[e]; fi[ofs] = pi[e];
            }
        }
        __syncthreads();
        const int m = s_m;           // == clo, in [50,96]
        if (tid < m) {
            float v = fv[tid]; int id = fi[tid];
            int r = 0;
            for (int q = 0; q < m; ++q) {
                float vq = fv[q];
                r += (vq > v) || (vq == v && fi[q] < id);   // smaller index wins ties
            }
            if (r < TOPK) {
                atomicAdd(&s_sum, v);
                if (anchor_label[id] == mylab) atomicAdd(&s_cm, 1);
            }
        }
    } else {
        // fallback: full exact rank scan (pathological value clustering only)
        for (int e0 = 0; e0 < ns; e0 += 256) {
            int e = e0 + tid;
            if (e < ns) {
                float v = pv[e]; int id = pi[e];
                int r = 0;
                for (int q = 0; q < ns; ++q) {
                    float vq = pv[q];
                    r += (vq > v) || (vq == v && pi[q] < id);
                }
                if (r < TOPK) {
                    atomicAdd(&s_sum, v);
                    if (anchor_label[id] == mylab) atomicAdd(&s_cm, 1);
                }
            }
        }
    }
    __syncthreads();
    if (tid == 0) {
        float mlp = (float)s_cm / (float)TOPK;
        out[row]          = -mlp;                 // loss
        out[B_ROWS + row] = s_sum / (float)TOPK;  // mean_sim
    }
}

extern "C" void kernel_launch(void* const* d_in, const int* in_sizes, int n_in,
                              void* d_out, int out_size, void* d_ws, size_t ws_size,
                              hipStream_t stream)
{
    const float* feat         = (const float*)d_in[0];
    const float* anc          = (const float*)d_in[1];
    const int*   labels       = (const int*)d_in[2];
    // d_in[3] = t_labels (unused)
    const int*   anchor_label = (const int*)d_in[4];
    float* out = (float*)d_out;

    char* ws = (char*)d_ws;
    size_t off = 0;
    unsigned short* fhi = (unsigned short*)(ws + off); off += (size_t)B_ROWS * DIM * 2; // 1.05 MB
    unsigned short* flo = (unsigned short*)(ws + off); off += (size_t)B_ROWS * DIM * 2;
    unsigned short* ahi = (unsigned short*)(ws + off); off += (size_t)N_ANCH * DIM * 2; // 25.6 MB
    unsigned short* alo = (unsigned short*)(ws + off); off += (size_t)N_ANCH * DIM * 2; // 25.6 MB
    float* sims = (float*)(ws + off);        off += (size_t)B_ROWS * NSAMP * 4;         // 33.5 MB
    uint2* cand = (uint2*)sims;              // overlay: row r's cand slice inside row r's sims
    int*   cnt  = (int*)(ws + off);          off += (size_t)B_ROWS * 4;
    float* Tarr = (float*)(ws + off);        off += (size_t)B_ROWS * 4;                 // ~86.9 MB total

    hipLaunchKernelGGL(split_bf16, dim3(256), dim3(256), 0, stream,
                       feat, fhi, flo, B_ROWS * DIM / 4);
    hipLaunchKernelGGL(split_bf16, dim3(4096), dim3(256), 0, stream,
                       anc, ahi, alo, N_ANCH * DIM / 4);
    hipLaunchKernelGGL(knn_sample_gemm, dim3(B_ROWS / BT, NCH), dim3(256), 0, stream,
                       fhi, flo, ahi, alo, sims);               // tile 0 of each chunk
    hipLaunchKernelGGL(bisect_thresh, dim3(B_ROWS), dim3(256), 0, stream,
                       sims, cand, cnt, Tarr);
    hipLaunchKernelGGL(knn_mfma_append, dim3(B_ROWS / BT, NCH, 3), dim3(256), 0, stream,
                       fhi, flo, ahi, alo, Tarr, cand, cnt);    // tiles 1..12, z-split
    hipLaunchKernelGGL(knn_final, dim3(B_ROWS), dim3(256), 0, stream,
                       cand, cnt, labels, anchor_label, out);
}